// Round 2
// baseline (753.378 us; speedup 1.0000x reference)
//
#include <hip/hip_runtime.h>
#include <math.h>
#include <stdint.h>

#define NN 50000
#define NE 200000
#define HD 768
#define TWOH 1536
#define DD1 256
#define NOUT 512
#define BM 128      // fallback tile
#define BK 64
#define KST 12      // node GEMM k-steps (HD/BK)
#define KSTEPS 24   // fallback kernel k-steps (TWOH/BK)

typedef __bf16 bf16_t;
typedef _Float16 f16_t;
typedef __attribute__((ext_vector_type(8))) __bf16 bf16x8;
typedef __attribute__((ext_vector_type(8))) _Float16 f16x8;
typedef __attribute__((ext_vector_type(4))) float f32x4;

__device__ __forceinline__ void gl2lds16(const void* g, void* l) {
    __builtin_amdgcn_global_load_lds(
        (const __attribute__((address_space(1))) unsigned int*)g,
        (__attribute__((address_space(3))) unsigned int*)l,
        16, 0, 0);
}

// ---- W1 f32 -> bf16, pre-swizzled [nb2][ks][kc][n][8]; value = W1[n][nb2*768 + ks*64 + kc*8 + u]
__global__ void swz_w1_kernel(const float* __restrict__ w1, bf16_t* __restrict__ w1s) {
    int idx = blockIdx.x * blockDim.x + threadIdx.x;   // 0 .. 2*12*8*256
    if (idx >= 2 * KST * 8 * 256) return;
    int n   = idx & 255;
    int kc  = (idx >> 8) & 7;
    int ksn = idx >> 11;                 // 0..23
    int nb2 = (ksn >= KST) ? 1 : 0;
    int ks  = ksn - nb2 * KST;
    const float* gp = w1 + (size_t)n * TWOH + nb2 * HD + ks * BK + kc * 8;
    float4 v0 = ((const float4*)gp)[0];
    float4 v1 = ((const float4*)gp)[1];
    bf16x8 o;
    o[0]=(bf16_t)v0.x; o[1]=(bf16_t)v0.y; o[2]=(bf16_t)v0.z; o[3]=(bf16_t)v0.w;
    o[4]=(bf16_t)v1.x; o[5]=(bf16_t)v1.y; o[6]=(bf16_t)v1.z; o[7]=(bf16_t)v1.w;
    *(bf16x8*)(w1s + (size_t)idx * 8) = o;
}

// ---- permuted b1 / w2 tables matching node_gemm's h store order ----
// stored s (within 256-half) = wn2*128 + r*8 + nb  -> orig c = wn2*128 + nb*16 + r
__global__ void prep_pw(const float* __restrict__ b1, const float* __restrict__ w2,
                        float* __restrict__ pw) {
    int s = threadIdx.x;    // 256
    int c = ((s >> 7) << 7) + ((s & 7) << 4) + ((s & 127) >> 3);
    pw[s]       = b1[c];
    pw[256 + s] = w2[c];
    pw[512 + s] = w2[DD1 + c];
}

__global__ void finalize_kernel(float* __restrict__ out, const float* __restrict__ accum) {
    out[0] = accum[0] / accum[1];
}

// ---- node projection GEMM: h[n][perm] = x[n] @ W1^T (raw, no bias/gelu), f16 out ----
// A path entirely in registers (wave-m-split), LDS only for the 32KB B tile.
__global__ __launch_bounds__(512, 6)
void node_gemm(const float* __restrict__ x, const bf16_t* __restrict__ w1s,
               f16_t* __restrict__ h)
{
    __shared__ __align__(16) char smem[32768];   // B: [8kc][256n][8] bf16

    const int t = threadIdx.x;
    const int lane = t & 63;
    const int wv = t >> 6;          // 0..7
    const int wm4 = wv >> 1;        // 16-row strip 0..3
    const int wn2 = wv & 1;         // 128-col half of the 256 band
    const int q = lane >> 4;        // 0..3
    const int r = lane & 15;

    // bijective XCD-chunked swizzle; nb2 pair of each mtile adjacent -> same XCD L2
    const int nwg = 782 * 2;                 // 1564
    const int qq = nwg >> 3, rr8 = nwg & 7;  // 195, 4
    int bid = blockIdx.x;
    int xcd = bid & 7, ii = bid >> 3;
    int wg = (xcd < rr8 ? xcd * (qq + 1) : rr8 * (qq + 1) + (xcd - rr8) * qq) + ii;
    const int mtile = wg >> 1;
    const int nb2 = wg & 1;

    int rowA = mtile * 64 + wm4 * 16 + r;
    const int growOK = rowA;                  // for store guard
    if (rowA >= NN) rowA = NN - 1;            // clamp loads (stores guarded)
    const float* xrow = x + (size_t)rowA * HD + q * 8;

    f32x4 acc[8];
    #pragma unroll
    for (int i = 0; i < 8; ++i) acc[i] = (f32x4){0.f, 0.f, 0.f, 0.f};

    float4 pr[4];
    auto loadA = [&](int ks) {
        const float* bp = xrow + ks * BK;
        pr[0] = *(const float4*)(bp);          // kk=0 lo
        pr[1] = *(const float4*)(bp + 4);      // kk=0 hi
        pr[2] = *(const float4*)(bp + 32);     // kk=1 lo
        pr[3] = *(const float4*)(bp + 36);     // kk=1 hi
    };

    bf16_t* Bl = (bf16_t*)smem;
    const bf16_t* w1base = w1s + (size_t)nb2 * KST * 16384;

    // prologue: issue A(0)
    loadA(0);

    for (int ks = 0; ks < KST; ++ks) {
        __syncthreads();   // B1: all waves done reading B(ks-1); drains outstanding A loads

        // stage B(ks): 4 gl2lds/thread, lane-linear, coalesced (pre-swizzled w1s)
        #pragma unroll
        for (int i = 0; i < 4; ++i) {
            const int ci = i * 512 + t;
            gl2lds16(w1base + (size_t)ks * 16384 + (size_t)ci * 8, Bl + ci * 8);
        }
        __builtin_amdgcn_sched_barrier(0);

        // convert A(ks) (complete since B1 drain) -> fragments
        bf16x8 af[2];
        #pragma unroll
        for (int kk = 0; kk < 2; ++kk) {
            af[kk][0]=(bf16_t)pr[2*kk].x; af[kk][1]=(bf16_t)pr[2*kk].y;
            af[kk][2]=(bf16_t)pr[2*kk].z; af[kk][3]=(bf16_t)pr[2*kk].w;
            af[kk][4]=(bf16_t)pr[2*kk+1].x; af[kk][5]=(bf16_t)pr[2*kk+1].y;
            af[kk][6]=(bf16_t)pr[2*kk+1].z; af[kk][7]=(bf16_t)pr[2*kk+1].w;
        }
        // issue A(ks+1) into pr; stays in flight across the MFMA phase
        const bool pf = (ks + 1 < KST);
        if (pf) loadA(ks + 1);
        __builtin_amdgcn_sched_barrier(0);

        // B2: wait only the 4 B gl2lds (A(ks+1) younger, keeps flying)
        if (pf) asm volatile("s_waitcnt vmcnt(4)\n\ts_barrier" ::: "memory");
        else    asm volatile("s_waitcnt vmcnt(0)\n\ts_barrier" ::: "memory");

        #pragma unroll
        for (int kk = 0; kk < 2; ++kk) {
            #pragma unroll
            for (int nb = 0; nb < 8; ++nb) {
                bf16x8 bfr = *(const bf16x8*)(Bl + (size_t)(((kk * 4 + q) << 8) + wn2 * 128 + nb * 16 + r) * 8);
                acc[nb] = __builtin_amdgcn_mfma_f32_16x16x32_bf16(af[kk], bfr, acc[nb], 0, 0, 0);
            }
        }
    }

    // epilogue: permuted f16x8 stores, 16B/lane fully coalesced
    // out row = wm4*16 + q*4 + rr ; stored col s = wn2*128 + r*8 + nb (orig c = wn2*128+nb*16+r)
    #pragma unroll
    for (int rr = 0; rr < 4; ++rr) {
        const int grow = mtile * 64 + wm4 * 16 + q * 4 + rr;
        if (grow < NN) {
            f16x8 o;
            #pragma unroll
            for (int nb = 0; nb < 8; ++nb) o[nb] = (f16_t)acc[nb][rr];
            *(f16x8*)(h + (size_t)grow * NOUT + nb2 * DD1 + wn2 * 128 + r * 8) = o;
        }
    }
    (void)growOK;
}

// ---- edge pass: gather P[src]+Q[dst] (permuted f16) -> gelu -> 256x2 linear -> softmax/CE
__global__ __launch_bounds__(256, 6)
void edge_mlp3(const f16_t* __restrict__ h, const float* __restrict__ pw,
               const float* __restrict__ b2, const float* __restrict__ cw,
               const int* __restrict__ esrc, const int* __restrict__ edst,
               const int* __restrict__ lab, float* __restrict__ out,
               float* __restrict__ accum)
{
    __shared__ float lds_pw[768];
    __shared__ float red[8];
    const int t = threadIdx.x;
    const int lane = t & 63;
    const int wv = t >> 6;          // 0..3
    const int slot = t >> 3;        // 0..31
    const int p = t & 7;            // 8 lanes per edge

    for (int i = t; i < 768; i += 256) lds_pw[i] = pw[i];
    __syncthreads();

    float wnll_t = 0.f, wsum_t = 0.f;
    const int eb = blockIdx.x * 128;

    #pragma unroll
    for (int j = 0; j < 4; ++j) {
        const int e = eb + j * 32 + slot;
        if (e < NE) {
            const int src = esrc[e];
            const int dst = edst[e];
            const f16_t* sp = h + (size_t)src * NOUT;
            const f16_t* dp = h + (size_t)dst * NOUT + DD1;
            float l0 = 0.f, l1 = 0.f;
            #pragma unroll
            for (int g = 0; g < 4; ++g) {
                const int c0 = g * 64 + p * 8;
                f16x8 ha = *(const f16x8*)(sp + c0);
                f16x8 hb = *(const f16x8*)(dp + c0);
                float4 ba = *(const float4*)(&lds_pw[c0]);
                float4 bb = *(const float4*)(&lds_pw[c0 + 4]);
                float4 wa = *(const float4*)(&lds_pw[256 + c0]);
                float4 wb = *(const float4*)(&lds_pw[256 + c0 + 4]);
                float4 va = *(const float4*)(&lds_pw[512 + c0]);
                float4 vb = *(const float4*)(&lds_pw[512 + c0 + 4]);
                const float bbv[8] = {ba.x,ba.y,ba.z,ba.w,bb.x,bb.y,bb.z,bb.w};
                const float w0v[8] = {wa.x,wa.y,wa.z,wa.w,wb.x,wb.y,wb.z,wb.w};
                const float w1v[8] = {va.x,va.y,va.z,va.w,vb.x,vb.y,vb.z,vb.w};
                #pragma unroll
                for (int u = 0; u < 8; ++u) {
                    float v = (float)ha[u] + (float)hb[u] + bbv[u];
                    float gl = 0.5f * v * (1.f + erff(v * 0.70710678118654752f));
                    l0 += gl * w0v[u];
                    l1 += gl * w1v[u];
                }
            }
            l0 += __shfl_xor(l0, 1); l0 += __shfl_xor(l0, 2); l0 += __shfl_xor(l0, 4);
            l1 += __shfl_xor(l1, 1); l1 += __shfl_xor(l1, 2); l1 += __shfl_xor(l1, 4);
            if (p == 0) {
                float L0 = l0 + b2[0], L1 = l1 + b2[1];
                float mx = fmaxf(L0, L1);
                float e0 = expf(L0 - mx), e1 = expf(L1 - mx);
                float s = e0 + e1, inv = 1.f / s;
                out[1 + 2 * e] = e0 * inv;
                out[2 + 2 * e] = e1 * inv;
                int lb = lab[e];
                float w = cw[lb];
                wnll_t += w * (mx + logf(s) - (lb ? L1 : L0));
                wsum_t += w;
            }
        }
    }
    #pragma unroll
    for (int o = 1; o < 64; o <<= 1) {
        wnll_t += __shfl_xor(wnll_t, o);
        wsum_t += __shfl_xor(wsum_t, o);
    }
    if (lane == 0) { red[wv] = wnll_t; red[4 + wv] = wsum_t; }
    __syncthreads();
    if (t == 0) {
        float a_ = red[0] + red[1] + red[2] + red[3];
        float b_ = red[4] + red[5] + red[6] + red[7];
        atomicAdd(&accum[0], a_);
        atomicAdd(&accum[1], b_);
    }
}

// ================== safety fallback: original proven fused kernel ==================
__global__ __launch_bounds__(512, 4)
void fused_edge_mlp(const float* __restrict__ xf,
                    const float* __restrict__ w1f,
                    const float* __restrict__ b1, const float* __restrict__ w2,
                    const float* __restrict__ b2, const float* __restrict__ cw,
                    const int* __restrict__ esrc, const int* __restrict__ edst,
                    const int* __restrict__ lab, float* __restrict__ out,
                    float* __restrict__ accum)
{
    __shared__ __align__(16) char smem[65536];
    const int t = threadIdx.x;
    const int lane = t & 63;
    const int wv = t >> 6;
    const int wm = wv & 1;
    const int wn = wv >> 1;
    const int q = lane >> 4;
    const int r = lane & 15;
    const int ebase = blockIdx.x * BM;
    const int r0 = t >> 3;
    const int e1c = (ebase + r0 + 64 < NE) ? (ebase + r0 + 64) : 0;
    const int ns0 = esrc[ebase + r0];
    const int nd0 = edst[ebase + r0];
    const int ns1 = esrc[e1c];
    const int nd1 = edst[e1c];
    const int gsl = (t & 7) ^ (r0 & 7);

    f32x4 acc[4][4];
    #pragma unroll
    for (int a_ = 0; a_ < 4; ++a_)
        #pragma unroll
        for (int b_ = 0; b_ < 4; ++b_) acc[a_][b_] = (f32x4){0.f, 0.f, 0.f, 0.f};

    auto stageA = [&](int kp, char* AbBase) {
        const bool issrc = (kp < 12);
        const int col0 = issrc ? kp * BK : kp * BK - HD;
        #pragma unroll
        for (int i = 0; i < 2; ++i) {
            const int node = i ? (issrc ? ns1 : nd1) : (issrc ? ns0 : nd0);
            bf16_t* lp = (bf16_t*)AbBase + i * 4096 + t * 8;
            const float* gp = xf + (size_t)node * HD + col0 + gsl * 8;
            float4 v0 = ((const float4*)gp)[0];
            float4 v1 = ((const float4*)gp)[1];
            bf16x8 o;
            o[0]=(bf16_t)v0.x; o[1]=(bf16_t)v0.y; o[2]=(bf16_t)v0.z; o[3]=(bf16_t)v0.w;
            o[4]=(bf16_t)v1.x; o[5]=(bf16_t)v1.y; o[6]=(bf16_t)v1.z; o[7]=(bf16_t)v1.w;
            *(bf16x8*)lp = o;
        }
    };

    stageA(0, smem);

    for (int ks = 0; ks < KSTEPS; ++ks) {
        bf16_t* Ac = (bf16_t*)(smem + ((ks & 1) << 14));
        char*   An = smem + ((~ks & 1) << 14);
        bf16_t* Bl = (bf16_t*)(smem + 32768);
        __syncthreads();
        #pragma unroll
        for (int i = 0; i < 4; ++i) {
            const int ci = i * 512 + t;
            bf16_t* lp = Bl + ci * 8;
            const int n = ci & 255, kc = ci >> 8;
            const float* gp = w1f + (size_t)n * TWOH + ks * BK + kc * 8;
            float4 v0 = ((const float4*)gp)[0];
            float4 v1 = ((const float4*)gp)[1];
            bf16x8 o;
            o[0]=(bf16_t)v0.x; o[1]=(bf16_t)v0.y; o[2]=(bf16_t)v0.z; o[3]=(bf16_t)v0.w;
            o[4]=(bf16_t)v1.x; o[5]=(bf16_t)v1.y; o[6]=(bf16_t)v1.z; o[7]=(bf16_t)v1.w;
            *(bf16x8*)lp = o;
        }
        __syncthreads();
        if (ks + 1 < KSTEPS) stageA(ks + 1, An);
        #pragma unroll
        for (int kk = 0; kk < 2; ++kk) {
            bf16x8 af[4];
            const int sl = (kk * 4 + q) ^ (r & 7);
            #pragma unroll
            for (int mb = 0; mb < 4; ++mb) {
                const int m = wm * 64 + mb * 16 + r;
                af[mb] = *(const bf16x8*)(Ac + m * 64 + sl * 8);
            }
            #pragma unroll
            for (int nb = 0; nb < 4; ++nb) {
                bf16x8 bfr = *(const bf16x8*)(Bl + (size_t)(((kk * 4 + q) << 8) + wn * 64 + nb * 16 + r) * 8);
                #pragma unroll
                for (int mb = 0; mb < 4; ++mb)
                    acc[mb][nb] = __builtin_amdgcn_mfma_f32_16x16x32_bf16(af[mb], bfr, acc[mb][nb], 0, 0, 0);
            }
        }
    }

    bf16_t* Hl = (bf16_t*)smem;
    float* red = (float*)(smem + 32768);
    float bias[4];
    #pragma unroll
    for (int nb = 0; nb < 4; ++nb) bias[nb] = b1[wn * 64 + nb * 16 + r];

    float wnll_t = 0.f, wsum_t = 0.f;
    const int ml2 = t >> 3;
    const int p = t & 7;

    #pragma unroll
    for (int half = 0; half < 2; ++half) {
        __syncthreads();
        if (wm == half) {
            #pragma unroll
            for (int mb = 0; mb < 4; ++mb)
                #pragma unroll
                for (int nb = 0; nb < 4; ++nb)
                    #pragma unroll
                    for (int rr = 0; rr < 4; ++rr) {
                        int ml = mb * 16 + q * 4 + rr;
                        int col = wn * 64 + nb * 16 + r;
                        float v = acc[mb][nb][rr] + bias[nb];
                        float g = 0.5f * v * (1.f + erff(v * 0.70710678118654752f));
                        int swcol = ((((col >> 3) ^ (ml & 7)) << 3) | (col & 7));
                        Hl[ml * 256 + swcol] = (bf16_t)g;
                    }
        }
        __syncthreads();
        float l0 = 0.f, l1 = 0.f;
        #pragma unroll
        for (int j = 0; j < 4; ++j) {
            int cj = p * 4 + j;
            bf16x8 hv = *(const bf16x8*)(Hl + ml2 * 256 + ((cj ^ (ml2 & 7)) << 3));
            const float4* w2a = (const float4*)(w2 + cj * 8);
            const float4* w2b = (const float4*)(w2 + 256 + cj * 8);
            float4 wa0 = w2a[0], wa1 = w2a[1], wb0 = w2b[0], wb1 = w2b[1];
            float hf[8];
            #pragma unroll
            for (int u = 0; u < 8; ++u) hf[u] = (float)hv[u];
            l0 += hf[0]*wa0.x + hf[1]*wa0.y + hf[2]*wa0.z + hf[3]*wa0.w
                + hf[4]*wa1.x + hf[5]*wa1.y + hf[6]*wa1.z + hf[7]*wa1.w;
            l1 += hf[0]*wb0.x + hf[1]*wb0.y + hf[2]*wb0.z + hf[3]*wb0.w
                + hf[4]*wb1.x + hf[5]*wb1.y + hf[6]*wb1.z + hf[7]*wb1.w;
        }
        l0 += __shfl_xor(l0, 1); l0 += __shfl_xor(l0, 2); l0 += __shfl_xor(l0, 4);
        l1 += __shfl_xor(l1, 1); l1 += __shfl_xor(l1, 2); l1 += __shfl_xor(l1, 4);
        const int eg = ebase + half * 64 + ml2;
        if (p == 0 && eg < NE) {
            l0 += b2[0]; l1 += b2[1];
            float mx = fmaxf(l0, l1);
            float e0 = expf(l0 - mx), e1 = expf(l1 - mx);
            float s = e0 + e1;
            float inv = 1.f / s;
            out[1 + 2 * eg] = e0 * inv;
            out[2 + 2 * eg] = e1 * inv;
            int lb = lab[eg];
            float w = cw[lb];
            float lpv = ((lb ? l1 : l0) - mx) - logf(s);
            wnll_t -= w * lpv;
            wsum_t += w;
        }
    }
    #pragma unroll
    for (int o = 1; o < 64; o <<= 1) {
        wnll_t += __shfl_xor(wnll_t, o);
        wsum_t += __shfl_xor(wsum_t, o);
    }
    __syncthreads();
    if (lane == 0) { red[wv] = wnll_t; red[8 + wv] = wsum_t; }
    __syncthreads();
    if (t == 0) {
        float a_ = 0.f, b_ = 0.f;
        #pragma unroll
        for (int i = 0; i < 8; ++i) { a_ += red[i]; b_ += red[8 + i]; }
        atomicAdd(&accum[0], a_);
        atomicAdd(&accum[1], b_);
    }
}

extern "C" void kernel_launch(void* const* d_in, const int* in_sizes, int n_in,
                              void* d_out, int out_size, void* d_ws, size_t ws_size,
                              hipStream_t stream)
{
    (void)in_sizes; (void)n_in; (void)out_size;
    const float* x  = (const float*)d_in[0];
    const float* W1 = (const float*)d_in[1];
    const float* b1 = (const float*)d_in[2];
    const float* W2 = (const float*)d_in[3];
    const float* b2 = (const float*)d_in[4];
    const float* cw = (const float*)d_in[5];
    const int* esrc = (const int*)d_in[6];
    const int* edst = (const int*)d_in[7];
    const int* lab  = (const int*)d_in[8];
    float* out = (float*)d_out;
    char* ws = (char*)d_ws;

    float* accum = (float*)ws;
    const size_t off_w1 = 256;
    const size_t w1s_bytes = (size_t)NOUT * HD * 2;      // 786432
    const size_t off_pw = off_w1 + w1s_bytes;            // 786688
    const size_t pw_bytes = 768 * sizeof(float);         // 3072
    const size_t off_h = off_pw + pw_bytes;              // 789760 (16B aligned)
    const size_t h_bytes = (size_t)NN * NOUT * 2;        // 51.2 MB

    (void)hipMemsetAsync(accum, 0, 2 * sizeof(float), stream);

    if (ws_size >= off_h + h_bytes) {
        bf16_t* w1s = (bf16_t*)(ws + off_w1);
        float* pw = (float*)(ws + off_pw);
        f16_t* h = (f16_t*)(ws + off_h);
        int nsw = 2 * KST * 8 * 256;
        swz_w1_kernel<<<(nsw + 255) / 256, 256, 0, stream>>>(W1, w1s);
        prep_pw<<<1, 256, 0, stream>>>(b1, W2, pw);
        node_gemm<<<782 * 2, 512, 0, stream>>>(x, w1s, h);
        edge_mlp3<<<(NE + 127) / 128, 256, 0, stream>>>(h, pw, b2, cw, esrc, edst, lab, out, accum);
    } else {
        dim3 grid((NE + BM - 1) / BM);
        fused_edge_mlp<<<grid, 512, 0, stream>>>(
            x, W1, b1, W2, b2, cw, esrc, edst, lab, out, accum);
    }

    finalize_kernel<<<1, 1, 0, stream>>>(out, accum);
}

// Round 3
// 538.002 us; speedup vs baseline: 1.4003x; 1.4003x over previous
//
#include <hip/hip_runtime.h>
#include <math.h>
#include <stdint.h>

#define NN 50000
#define NE 200000
#define HD 768
#define TWOH 1536
#define DD1 256
#define NOUT 512
#define BM 128
#define BK 64
#define KST 12      // node GEMM k-steps (HD/BK)
#define KSTEPS 24   // fused fallback k-steps (TWOH/BK)

typedef __bf16 bf16_t;
typedef _Float16 f16_t;
typedef __attribute__((ext_vector_type(8))) __bf16 bf16x8;
typedef __attribute__((ext_vector_type(8))) _Float16 f16x8;
typedef __attribute__((ext_vector_type(4))) _Float16 f16x4;
typedef __attribute__((ext_vector_type(4))) float f32x4;

__device__ __forceinline__ void gl2lds16(const void* g, void* l) {
    __builtin_amdgcn_global_load_lds(
        (const __attribute__((address_space(1))) unsigned int*)g,
        (__attribute__((address_space(3))) unsigned int*)l,
        16, 0, 0);
}

// ---- f32 -> bf16 cast, 16 elems/thread (round-0 proven) ----
__global__ void cvt16_kernel(const float* __restrict__ in, bf16_t* __restrict__ out, int n16) {
    int i = blockIdx.x * blockDim.x + threadIdx.x;
    if (i >= n16) return;
    const float4* p = (const float4*)in + (size_t)i * 4;
    float4 a = p[0], b = p[1], c = p[2], d = p[3];
    bf16x8 o0, o1;
    o0[0]=(bf16_t)a.x; o0[1]=(bf16_t)a.y; o0[2]=(bf16_t)a.z; o0[3]=(bf16_t)a.w;
    o0[4]=(bf16_t)b.x; o0[5]=(bf16_t)b.y; o0[6]=(bf16_t)b.z; o0[7]=(bf16_t)b.w;
    o1[0]=(bf16_t)c.x; o1[1]=(bf16_t)c.y; o1[2]=(bf16_t)c.z; o1[3]=(bf16_t)c.w;
    o1[4]=(bf16_t)d.x; o1[5]=(bf16_t)d.y; o1[6]=(bf16_t)d.z; o1[7]=(bf16_t)d.w;
    bf16x8* q = (bf16x8*)(out + (size_t)i * 16);
    q[0] = o0; q[1] = o1;
}

// ---- W1 f32 -> bf16, pre-swizzled [ks24][kc][n][8] (same layout as round-0) ----
__global__ void swz_w1_kernel(const float* __restrict__ w1, bf16_t* __restrict__ w1s) {
    int idx = blockIdx.x * blockDim.x + threadIdx.x;   // 0 .. 24*8*256
    if (idx >= KSTEPS * 8 * 256) return;
    int n  = idx & 255;
    int kc = (idx >> 8) & 7;
    int ks = idx >> 11;                 // 0..23 over TWOH
    const float* gp = w1 + (size_t)n * TWOH + ks * BK + kc * 8;
    float4 v0 = ((const float4*)gp)[0];
    float4 v1 = ((const float4*)gp)[1];
    bf16x8 o;
    o[0]=(bf16_t)v0.x; o[1]=(bf16_t)v0.y; o[2]=(bf16_t)v0.z; o[3]=(bf16_t)v0.w;
    o[4]=(bf16_t)v1.x; o[5]=(bf16_t)v1.y; o[6]=(bf16_t)v1.z; o[7]=(bf16_t)v1.w;
    *(bf16x8*)(w1s + (size_t)idx * 8) = o;
}

// ---- permuted b1/w2 matching node_gemm3's h store order ----
// stored s (within 256-half): s = wn*64 + r*4 + nb  <->  orig c = wn*64 + nb*16 + r
__global__ void prep_pw(const float* __restrict__ b1, const float* __restrict__ w2,
                        float* __restrict__ pw) {
    int s = threadIdx.x;    // 0..255
    int k = s & 63;
    int c = (s & 192) + ((k & 3) << 4) + (k >> 2);
    pw[s]       = b1[c];
    pw[256 + s] = w2[c];
    pw[512 + s] = w2[DD1 + c];
}

__global__ void finalize_kernel(float* __restrict__ out, const float* __restrict__ accum) {
    out[0] = accum[0] / accum[1];
}

// ---- node projection GEMM (round-1 loop, gl2lds A from bf16 xb) ----
// h[n][perm(0:256)] = x[n] @ W1a^T ; h[n][perm(256:512)] = x[n] @ W1b^T  (raw, f16)
__global__ __launch_bounds__(512, 4)
void node_gemm3(const bf16_t* __restrict__ xb, const bf16_t* __restrict__ w1s,
                f16_t* __restrict__ h)
{
    // LDS: A0[128m][64k] 16KB @0 | A1 16KB @16384 | B[8kc][256n][8] 32KB @32768
    __shared__ __align__(16) char smem[65536];

    const int t = threadIdx.x;
    const int lane = t & 63;
    const int wv = t >> 6;
    const int wm = wv & 1;          // m-half
    const int wn = wv >> 1;         // 64-col quarter
    const int q = lane >> 4;
    const int r = lane & 15;

    // bijective XCD-chunked swizzle; nb2 pair of each mtile adjacent -> same XCD L2
    const int nwg = 391 * 2;                 // 782
    const int qq = nwg >> 3, rr8 = nwg & 7;  // 97, 6
    int bid = blockIdx.x;
    int xcd = bid & 7, ii = bid >> 3;
    int wg = (xcd < rr8 ? xcd * (qq + 1) : rr8 * (qq + 1) + (xcd - rr8) * qq) + ii;
    const int mtile = wg >> 1;
    const int nb2 = wg & 1;

    const int r0 = t >> 3;
    const int gsl = (t & 7) ^ (r0 & 7);      // xor-swizzled global chunk
    int row0 = mtile * BM + r0;        if (row0 >= NN) row0 = NN - 1;
    int row1 = mtile * BM + 64 + r0;   if (row1 >= NN) row1 = NN - 1;
    const bf16_t* gA0 = xb + (size_t)row0 * HD + gsl * 8;
    const bf16_t* gA1 = xb + (size_t)row1 * HD + gsl * 8;

    auto stageA = [&](int ks, char* Ab) {
        gl2lds16(gA0 + ks * BK, (bf16_t*)Ab + t * 8);
        gl2lds16(gA1 + ks * BK, (bf16_t*)Ab + 4096 + t * 8);
    };

    f32x4 acc[4][4];
    #pragma unroll
    for (int a_ = 0; a_ < 4; ++a_)
        #pragma unroll
        for (int b_ = 0; b_ < 4; ++b_) acc[a_][b_] = (f32x4){0.f, 0.f, 0.f, 0.f};

    const bf16_t* w1base = w1s + (size_t)nb2 * KST * 16384;

    stageA(0, smem);

    for (int ks = 0; ks < KST; ++ks) {
        bf16_t* Ac = (bf16_t*)(smem + ((ks & 1) << 14));
        char*   An = smem + ((~ks & 1) << 14);
        bf16_t* Bl = (bf16_t*)(smem + 32768);

        __syncthreads();   // B1: drains A(ks); prev-step LDS reads done

        // stage B(ks): 4 gl2lds/thread, lane-linear, coalesced
        #pragma unroll
        for (int i = 0; i < 4; ++i) {
            const int ci = i * 512 + t;
            gl2lds16(w1base + (size_t)ks * 16384 + (size_t)ci * 8, Bl + ci * 8);
        }
        // prefetch A(ks+1); stays in flight across the MFMA phase
        const bool pf = (ks + 1 < KST);
        if (pf) stageA(ks + 1, An);

        // B2: wait only the 4 B gl2lds (issued first -> vmcnt(2) leaves A flying)
        if (pf) asm volatile("s_waitcnt vmcnt(2)\n\ts_barrier" ::: "memory");
        else    asm volatile("s_waitcnt vmcnt(0)\n\ts_barrier" ::: "memory");

        #pragma unroll
        for (int kk = 0; kk < 2; ++kk) {
            bf16x8 af[4];
            const int sl = (kk * 4 + q) ^ (r & 7);
            #pragma unroll
            for (int mb = 0; mb < 4; ++mb)
                af[mb] = *(const bf16x8*)(Ac + (wm * 64 + mb * 16 + r) * 64 + sl * 8);
            #pragma unroll
            for (int nb = 0; nb < 4; ++nb) {
                bf16x8 bfr = *(const bf16x8*)(Bl + (size_t)(((kk * 4 + q) << 8) + wn * 64 + nb * 16 + r) * 8);
                #pragma unroll
                for (int mb = 0; mb < 4; ++mb)
                    acc[mb][nb] = __builtin_amdgcn_mfma_f32_16x16x32_bf16(af[mb], bfr, acc[mb][nb], 0, 0, 0);
            }
        }
    }

    // epilogue: permuted f16x4 stores (8B/lane, 128B contiguous per q-group)
    // row = wm*64 + mb*16 + q*4 + rr ; cols s = wn*64 + r*4 + {0..3} (orig c = wn*64+nb*16+r)
    #pragma unroll
    for (int mb = 0; mb < 4; ++mb) {
        #pragma unroll
        for (int rr = 0; rr < 4; ++rr) {
            const int grow = mtile * BM + wm * 64 + mb * 16 + q * 4 + rr;
            if (grow < NN) {
                f16x4 o;
                #pragma unroll
                for (int nb = 0; nb < 4; ++nb) o[nb] = (f16_t)acc[mb][nb][rr];
                *(f16x4*)(h + (size_t)grow * NOUT + nb2 * DD1 + wn * 64 + r * 4) = o;
            }
        }
    }
}

// ---- edge pass: batched 16-deep gathers -> gelu -> 256x2 linear -> softmax/CE ----
__global__ __launch_bounds__(256, 4)
void edge_mlp4(const f16_t* __restrict__ h, const float* __restrict__ pw,
               const float* __restrict__ b2, const float* __restrict__ cw,
               const int* __restrict__ esrc, const int* __restrict__ edst,
               const int* __restrict__ lab, float* __restrict__ out,
               float* __restrict__ accum)
{
    __shared__ float lds_pw[768];
    __shared__ float red[8];
    const int t = threadIdx.x;
    const int lane = t & 63;
    const int wv = t >> 6;          // 0..3
    const int slot = t >> 3;        // 0..31
    const int p = t & 7;            // 8 lanes per edge

    for (int i = t; i < 768; i += 256) lds_pw[i] = pw[i];

    const int eb = blockIdx.x * 64;           // 3125 * 64 = NE exactly
    const int e0 = eb + slot, e1 = eb + 32 + slot;
    const int s0 = esrc[e0], d0 = edst[e0];
    const int s1 = esrc[e1], d1 = edst[e1];
    const char* hB = (const char*)h;
    const uint32_t o_s0 = (uint32_t)s0 * 1024u + (uint32_t)p * 16u;
    const uint32_t o_d0 = (uint32_t)d0 * 1024u + 512u + (uint32_t)p * 16u;
    const uint32_t o_s1 = (uint32_t)s1 * 1024u + (uint32_t)p * 16u;
    const uint32_t o_d1 = (uint32_t)d1 * 1024u + 512u + (uint32_t)p * 16u;

    // batch ALL 16 gathers (MLP) before any compute
    f16x8 A0[4], B0[4], A1[4], B1v[4];
    #pragma unroll
    for (int g = 0; g < 4; ++g) {
        A0[g]  = *(const f16x8*)(hB + o_s0 + g * 128);
        B0[g]  = *(const f16x8*)(hB + o_d0 + g * 128);
        A1[g]  = *(const f16x8*)(hB + o_s1 + g * 128);
        B1v[g] = *(const f16x8*)(hB + o_d1 + g * 128);
    }
    __builtin_amdgcn_sched_barrier(0);
    __syncthreads();   // lds_pw ready; loads drained (all were in flight together)

    float wnll_t = 0.f, wsum_t = 0.f;

    #pragma unroll
    for (int j = 0; j < 2; ++j) {
        float l0 = 0.f, l1 = 0.f;
        #pragma unroll
        for (int g = 0; g < 4; ++g) {
            const int c0 = g * 64 + p * 8;
            f16x8 ha = j ? A1[g] : A0[g];
            f16x8 hb = j ? B1v[g] : B0[g];
            float4 ba = *(const float4*)(&lds_pw[c0]);
            float4 bb = *(const float4*)(&lds_pw[c0 + 4]);
            float4 wa = *(const float4*)(&lds_pw[256 + c0]);
            float4 wb = *(const float4*)(&lds_pw[256 + c0 + 4]);
            float4 va = *(const float4*)(&lds_pw[512 + c0]);
            float4 vb = *(const float4*)(&lds_pw[512 + c0 + 4]);
            const float bbv[8] = {ba.x,ba.y,ba.z,ba.w,bb.x,bb.y,bb.z,bb.w};
            const float w0v[8] = {wa.x,wa.y,wa.z,wa.w,wb.x,wb.y,wb.z,wb.w};
            const float w1v[8] = {va.x,va.y,va.z,va.w,vb.x,vb.y,vb.z,vb.w};
            #pragma unroll
            for (int u = 0; u < 8; ++u) {
                float v = (float)ha[u] + (float)hb[u] + bbv[u];
                float gl = 0.5f * v * (1.f + erff(v * 0.70710678118654752f));
                l0 += gl * w0v[u];
                l1 += gl * w1v[u];
            }
        }
        l0 += __shfl_xor(l0, 1); l0 += __shfl_xor(l0, 2); l0 += __shfl_xor(l0, 4);
        l1 += __shfl_xor(l1, 1); l1 += __shfl_xor(l1, 2); l1 += __shfl_xor(l1, 4);
        if (p == 0) {
            const int e = j ? e1 : e0;
            float L0 = l0 + b2[0], L1 = l1 + b2[1];
            float mx = fmaxf(L0, L1);
            float ex0 = expf(L0 - mx), ex1 = expf(L1 - mx);
            float s = ex0 + ex1, inv = 1.f / s;
            out[1 + 2 * e] = ex0 * inv;
            out[2 + 2 * e] = ex1 * inv;
            int lb = lab[e];
            float w = cw[lb];
            wnll_t += w * (mx + logf(s) - (lb ? L1 : L0));
            wsum_t += w;
        }
    }
    // reduce over p==0 lanes (lanes 0,8,..,56) then across waves
    wnll_t += __shfl_xor(wnll_t, 8);  wsum_t += __shfl_xor(wsum_t, 8);
    wnll_t += __shfl_xor(wnll_t, 16); wsum_t += __shfl_xor(wsum_t, 16);
    wnll_t += __shfl_xor(wnll_t, 32); wsum_t += __shfl_xor(wsum_t, 32);
    if (lane == 0) { red[wv] = wnll_t; red[4 + wv] = wsum_t; }
    __syncthreads();
    if (t == 0) {
        float a_ = red[0] + red[1] + red[2] + red[3];
        float b_ = red[4] + red[5] + red[6] + red[7];
        atomicAdd(&accum[0], a_);
        atomicAdd(&accum[1], b_);
    }
}

// ================== round-0 proven fused kernel (tiers 2/3) ==================
template<bool XPRE, bool WPRE>
__global__ __launch_bounds__(512, 4)
void fused_edge_mlp(const float* __restrict__ xf, const bf16_t* __restrict__ xb,
                    const float* __restrict__ w1f, const bf16_t* __restrict__ w1s,
                    const float* __restrict__ b1, const float* __restrict__ w2,
                    const float* __restrict__ b2, const float* __restrict__ cw,
                    const int* __restrict__ esrc, const int* __restrict__ edst,
                    const int* __restrict__ lab, float* __restrict__ out,
                    float* __restrict__ accum)
{
    __shared__ __align__(16) char smem[65536];
    const int t = threadIdx.x;
    const int lane = t & 63;
    const int wv = t >> 6;
    const int wm = wv & 1;
    const int wn = wv >> 1;
    const int q = lane >> 4;
    const int r = lane & 15;
    const int ebase = blockIdx.x * BM;
    const int r0 = t >> 3;
    const int e1c = (ebase + r0 + 64 < NE) ? (ebase + r0 + 64) : 0;
    const int ns0 = esrc[ebase + r0];
    const int nd0 = edst[ebase + r0];
    const int ns1 = esrc[e1c];
    const int nd1 = edst[e1c];
    const int gsl = (t & 7) ^ (r0 & 7);

    f32x4 acc[4][4];
    #pragma unroll
    for (int a_ = 0; a_ < 4; ++a_)
        #pragma unroll
        for (int b_ = 0; b_ < 4; ++b_) acc[a_][b_] = (f32x4){0.f, 0.f, 0.f, 0.f};

    auto stageA = [&](int kp, char* AbBase) {
        const bool issrc = (kp < 12);
        const int col0 = issrc ? kp * BK : kp * BK - HD;
        #pragma unroll
        for (int i = 0; i < 2; ++i) {
            const int node = i ? (issrc ? ns1 : nd1) : (issrc ? ns0 : nd0);
            bf16_t* lp = (bf16_t*)AbBase + i * 4096 + t * 8;
            if (XPRE) {
                gl2lds16(xb + (size_t)node * HD + col0 + gsl * 8, lp);
            } else {
                const float* gp = xf + (size_t)node * HD + col0 + gsl * 8;
                float4 v0 = ((const float4*)gp)[0];
                float4 v1 = ((const float4*)gp)[1];
                bf16x8 o;
                o[0]=(bf16_t)v0.x; o[1]=(bf16_t)v0.y; o[2]=(bf16_t)v0.z; o[3]=(bf16_t)v0.w;
                o[4]=(bf16_t)v1.x; o[5]=(bf16_t)v1.y; o[6]=(bf16_t)v1.z; o[7]=(bf16_t)v1.w;
                *(bf16x8*)lp = o;
            }
        }
    };

    stageA(0, smem);

    for (int ks = 0; ks < KSTEPS; ++ks) {
        bf16_t* Ac = (bf16_t*)(smem + ((ks & 1) << 14));
        char*   An = smem + ((~ks & 1) << 14);
        bf16_t* Bl = (bf16_t*)(smem + 32768);
        __syncthreads();
        #pragma unroll
        for (int i = 0; i < 4; ++i) {
            const int ci = i * 512 + t;
            bf16_t* lp = Bl + ci * 8;
            if (WPRE) {
                gl2lds16(w1s + (size_t)ks * 16384 + ci * 8, lp);
            } else {
                const int n = ci & 255, kc = ci >> 8;
                const float* gp = w1f + (size_t)n * TWOH + ks * BK + kc * 8;
                float4 v0 = ((const float4*)gp)[0];
                float4 v1 = ((const float4*)gp)[1];
                bf16x8 o;
                o[0]=(bf16_t)v0.x; o[1]=(bf16_t)v0.y; o[2]=(bf16_t)v0.z; o[3]=(bf16_t)v0.w;
                o[4]=(bf16_t)v1.x; o[5]=(bf16_t)v1.y; o[6]=(bf16_t)v1.z; o[7]=(bf16_t)v1.w;
                *(bf16x8*)lp = o;
            }
        }
        if (XPRE && WPRE)
            asm volatile("s_waitcnt vmcnt(0)\n\ts_barrier" ::: "memory");
        else
            __syncthreads();
        if (ks + 1 < KSTEPS) stageA(ks + 1, An);
        #pragma unroll
        for (int kk = 0; kk < 2; ++kk) {
            bf16x8 af[4];
            const int sl = (kk * 4 + q) ^ (r & 7);
            #pragma unroll
            for (int mb = 0; mb < 4; ++mb) {
                const int m = wm * 64 + mb * 16 + r;
                af[mb] = *(const bf16x8*)(Ac + m * 64 + sl * 8);
            }
            #pragma unroll
            for (int nb = 0; nb < 4; ++nb) {
                bf16x8 bfr = *(const bf16x8*)(Bl + (size_t)(((kk * 4 + q) << 8) + wn * 64 + nb * 16 + r) * 8);
                #pragma unroll
                for (int mb = 0; mb < 4; ++mb)
                    acc[mb][nb] = __builtin_amdgcn_mfma_f32_16x16x32_bf16(af[mb], bfr, acc[mb][nb], 0, 0, 0);
            }
        }
    }

    bf16_t* Hl = (bf16_t*)smem;
    float* red = (float*)(smem + 32768);
    float bias[4];
    #pragma unroll
    for (int nb = 0; nb < 4; ++nb) bias[nb] = b1[wn * 64 + nb * 16 + r];

    float wnll_t = 0.f, wsum_t = 0.f;
    const int ml2 = t >> 3;
    const int p = t & 7;

    #pragma unroll
    for (int half = 0; half < 2; ++half) {
        __syncthreads();
        if (wm == half) {
            #pragma unroll
            for (int mb = 0; mb < 4; ++mb)
                #pragma unroll
                for (int nb = 0; nb < 4; ++nb)
                    #pragma unroll
                    for (int rr = 0; rr < 4; ++rr) {
                        int ml = mb * 16 + q * 4 + rr;
                        int col = wn * 64 + nb * 16 + r;
                        float v = acc[mb][nb][rr] + bias[nb];
                        float g = 0.5f * v * (1.f + erff(v * 0.70710678118654752f));
                        int swcol = ((((col >> 3) ^ (ml & 7)) << 3) | (col & 7));
                        Hl[ml * 256 + swcol] = (bf16_t)g;
                    }
        }
        __syncthreads();
        float l0 = 0.f, l1 = 0.f;
        #pragma unroll
        for (int j = 0; j < 4; ++j) {
            int cj = p * 4 + j;
            bf16x8 hv = *(const bf16x8*)(Hl + ml2 * 256 + ((cj ^ (ml2 & 7)) << 3));
            const float4* w2a = (const float4*)(w2 + cj * 8);
            const float4* w2b = (const float4*)(w2 + 256 + cj * 8);
            float4 wa0 = w2a[0], wa1 = w2a[1], wb0 = w2b[0], wb1 = w2b[1];
            float hf[8];
            #pragma unroll
            for (int u = 0; u < 8; ++u) hf[u] = (float)hv[u];
            l0 += hf[0]*wa0.x + hf[1]*wa0.y + hf[2]*wa0.z + hf[3]*wa0.w
                + hf[4]*wa1.x + hf[5]*wa1.y + hf[6]*wa1.z + hf[7]*wa1.w;
            l1 += hf[0]*wb0.x + hf[1]*wb0.y + hf[2]*wb0.z + hf[3]*wb0.w
                + hf[4]*wb1.x + hf[5]*wb1.y + hf[6]*wb1.z + hf[7]*wb1.w;
        }
        l0 += __shfl_xor(l0, 1); l0 += __shfl_xor(l0, 2); l0 += __shfl_xor(l0, 4);
        l1 += __shfl_xor(l1, 1); l1 += __shfl_xor(l1, 2); l1 += __shfl_xor(l1, 4);
        const int eg = ebase + half * 64 + ml2;
        if (p == 0 && eg < NE) {
            l0 += b2[0]; l1 += b2[1];
            float mx = fmaxf(l0, l1);
            float e0 = expf(l0 - mx), e1 = expf(l1 - mx);
            float s = e0 + e1;
            float inv = 1.f / s;
            out[1 + 2 * eg] = e0 * inv;
            out[2 + 2 * eg] = e1 * inv;
            int lb = lab[eg];
            float w = cw[lb];
            float lpv = ((lb ? l1 : l0) - mx) - logf(s);
            wnll_t -= w * lpv;
            wsum_t += w;
        }
    }
    #pragma unroll
    for (int o = 1; o < 64; o <<= 1) {
        wnll_t += __shfl_xor(wnll_t, o);
        wsum_t += __shfl_xor(wsum_t, o);
    }
    __syncthreads();
    if (lane == 0) { red[wv] = wnll_t; red[8 + wv] = wsum_t; }
    __syncthreads();
    if (t == 0) {
        float a_ = 0.f, b_ = 0.f;
        #pragma unroll
        for (int i = 0; i < 8; ++i) { a_ += red[i]; b_ += red[8 + i]; }
        atomicAdd(&accum[0], a_);
        atomicAdd(&accum[1], b_);
    }
}

extern "C" void kernel_launch(void* const* d_in, const int* in_sizes, int n_in,
                              void* d_out, int out_size, void* d_ws, size_t ws_size,
                              hipStream_t stream)
{
    (void)in_sizes; (void)n_in; (void)out_size;
    const float* x  = (const float*)d_in[0];
    const float* W1 = (const float*)d_in[1];
    const float* b1 = (const float*)d_in[2];
    const float* W2 = (const float*)d_in[3];
    const float* b2 = (const float*)d_in[4];
    const float* cw = (const float*)d_in[5];
    const int* esrc = (const int*)d_in[6];
    const int* edst = (const int*)d_in[7];
    const int* lab  = (const int*)d_in[8];
    float* out = (float*)d_out;
    char* ws = (char*)d_ws;

    float* accum = (float*)ws;
    const size_t off_w1 = 256;
    const size_t w1s_bytes = (size_t)DD1 * TWOH * 2;     // 786432
    const size_t off_pw = off_w1 + w1s_bytes;            // 786688
    const size_t off_h  = off_pw + 3072;                 // 789760
    const size_t h_bytes = (size_t)NN * NOUT * 2;        // 51.2 MB
    const size_t off_xb = off_h + h_bytes;               // ~52.0 MB
    const size_t xb_bytes = (size_t)NN * HD * 2;         // 76.8 MB
    const size_t off_xb2 = off_h;                        // tier-2: xb where h would be

    (void)hipMemsetAsync(accum, 0, 2 * sizeof(float), stream);

    const int nsw = KSTEPS * 8 * 256;
    const int n16 = NN * HD / 16;

    if (ws_size >= off_xb + xb_bytes) {
        // tier 1: split node-GEMM + edge pass
        bf16_t* w1s = (bf16_t*)(ws + off_w1);
        float* pw = (float*)(ws + off_pw);
        f16_t* h = (f16_t*)(ws + off_h);
        bf16_t* xb = (bf16_t*)(ws + off_xb);
        swz_w1_kernel<<<(nsw + 255) / 256, 256, 0, stream>>>(W1, w1s);
        cvt16_kernel<<<(n16 + 255) / 256, 256, 0, stream>>>(x, xb, n16);
        prep_pw<<<1, 256, 0, stream>>>(b1, W2, pw);
        node_gemm3<<<391 * 2, 512, 0, stream>>>(xb, w1s, h);
        edge_mlp4<<<NE / 64, 256, 0, stream>>>(h, pw, b2, cw, esrc, edst, lab, out, accum);
    } else if (ws_size >= off_xb2 + xb_bytes) {
        // tier 2: round-0 proven fused path
        bf16_t* w1s = (bf16_t*)(ws + off_w1);
        bf16_t* xb = (bf16_t*)(ws + off_xb2);
        swz_w1_kernel<<<(nsw + 255) / 256, 256, 0, stream>>>(W1, w1s);
        cvt16_kernel<<<(n16 + 255) / 256, 256, 0, stream>>>(x, xb, n16);
        dim3 grid((NE + BM - 1) / BM);
        fused_edge_mlp<true, true><<<grid, 512, 0, stream>>>(
            x, xb, W1, w1s, b1, W2, b2, cw, esrc, edst, lab, out, accum);
    } else {
        dim3 grid((NE + BM - 1) / BM);
        fused_edge_mlp<false, false><<<grid, 512, 0, stream>>>(
            x, (const bf16_t*)ws, W1, (const bf16_t*)ws, b1, W2, b2, cw,
            esrc, edst, lab, out, accum);
    }

    finalize_kernel<<<1, 1, 0, stream>>>(out, accum);
}

// Round 4
// 454.269 us; speedup vs baseline: 1.6584x; 1.1843x over previous
//
#include <hip/hip_runtime.h>
#include <math.h>
#include <stdint.h>

#define NN 50000
#define NE 200000
#define HD 768
#define TWOH 1536
#define DD1 256
#define NOUT 512
#define BM 128
#define BK 64
#define KST 12      // node GEMM k-steps (HD/BK)
#define KSTEPS 24   // fused fallback k-steps (TWOH/BK)

#define NB_CVT 9375            // NN*HD/16/256
#define NB_SWZ 192             // KSTEPS*8*256/256

typedef __bf16 bf16_t;
typedef _Float16 f16_t;
typedef __attribute__((ext_vector_type(8))) __bf16 bf16x8;
typedef __attribute__((ext_vector_type(8))) _Float16 f16x8;
typedef __attribute__((ext_vector_type(4))) _Float16 f16x4;
typedef __attribute__((ext_vector_type(4))) float f32x4;

__device__ __forceinline__ void gl2lds16(const void* g, void* l) {
    __builtin_amdgcn_global_load_lds(
        (const __attribute__((address_space(1))) unsigned int*)g,
        (__attribute__((address_space(3))) unsigned int*)l,
        16, 0, 0);
}

// ---- fused prep: [0,NB_CVT) x->bf16 ; [NB_CVT,NB_CVT+NB_SWZ) W1 swizzle ; last block pw ----
__global__ void prep_all(const float* __restrict__ x, bf16_t* __restrict__ xb,
                         const float* __restrict__ w1, bf16_t* __restrict__ w1s,
                         const float* __restrict__ b1, const float* __restrict__ w2,
                         float* __restrict__ pw)
{
    const int b = blockIdx.x;
    const int t = threadIdx.x;
    if (b < NB_CVT) {
        // f32 -> bf16, 16 elems/thread
        const int i = b * 256 + t;
        const float4* p = (const float4*)x + (size_t)i * 4;
        float4 a = p[0], bq = p[1], c = p[2], d = p[3];
        bf16x8 o0, o1;
        o0[0]=(bf16_t)a.x; o0[1]=(bf16_t)a.y; o0[2]=(bf16_t)a.z; o0[3]=(bf16_t)a.w;
        o0[4]=(bf16_t)bq.x; o0[5]=(bf16_t)bq.y; o0[6]=(bf16_t)bq.z; o0[7]=(bf16_t)bq.w;
        o1[0]=(bf16_t)c.x; o1[1]=(bf16_t)c.y; o1[2]=(bf16_t)c.z; o1[3]=(bf16_t)c.w;
        o1[4]=(bf16_t)d.x; o1[5]=(bf16_t)d.y; o1[6]=(bf16_t)d.z; o1[7]=(bf16_t)d.w;
        bf16x8* q = (bf16x8*)(xb + (size_t)i * 16);
        q[0] = o0; q[1] = o1;
    } else if (b < NB_CVT + NB_SWZ) {
        // W1 f32 -> bf16, pre-swizzled [ks24][kc][n][8]
        const int idx = (b - NB_CVT) * 256 + t;
        const int n  = idx & 255;
        const int kc = (idx >> 8) & 7;
        const int ks = idx >> 11;
        const float* gp = w1 + (size_t)n * TWOH + ks * BK + kc * 8;
        float4 v0 = ((const float4*)gp)[0];
        float4 v1 = ((const float4*)gp)[1];
        bf16x8 o;
        o[0]=(bf16_t)v0.x; o[1]=(bf16_t)v0.y; o[2]=(bf16_t)v0.z; o[3]=(bf16_t)v0.w;
        o[4]=(bf16_t)v1.x; o[5]=(bf16_t)v1.y; o[6]=(bf16_t)v1.z; o[7]=(bf16_t)v1.w;
        *(bf16x8*)(w1s + (size_t)idx * 8) = o;
    } else {
        // permuted b1/w2: stored s = wn*64 + r*4 + nb  <->  orig c = wn*64 + nb*16 + r
        const int s = t;
        const int k = s & 63;
        const int c = (s & 192) + ((k & 3) << 4) + (k >> 2);
        pw[s]       = b1[c];
        pw[256 + s] = w2[c];
        pw[512 + s] = w2[DD1 + c];
    }
}

__global__ void finalize_kernel(float* __restrict__ out, const float* __restrict__ accum) {
    out[0] = accum[0] / accum[1];
}

// ---- node projection GEMM (proven round-3): h[n][perm] = x[n] @ W1^T, raw f16 ----
__global__ __launch_bounds__(512, 4)
void node_gemm3(const bf16_t* __restrict__ xb, const bf16_t* __restrict__ w1s,
                f16_t* __restrict__ h)
{
    // LDS: A0[128m][64k] 16KB @0 | A1 16KB @16384 | B[8kc][256n][8] 32KB @32768
    __shared__ __align__(16) char smem[65536];

    const int t = threadIdx.x;
    const int lane = t & 63;
    const int wv = t >> 6;
    const int wm = wv & 1;          // m-half
    const int wn = wv >> 1;         // 64-col quarter
    const int q = lane >> 4;
    const int r = lane & 15;

    // bijective XCD-chunked swizzle; nb2 pair of each mtile adjacent -> same XCD L2
    const int nwg = 391 * 2;                 // 782
    const int qq = nwg >> 3, rr8 = nwg & 7;  // 97, 6
    int bid = blockIdx.x;
    int xcd = bid & 7, ii = bid >> 3;
    int wg = (xcd < rr8 ? xcd * (qq + 1) : rr8 * (qq + 1) + (xcd - rr8) * qq) + ii;
    const int mtile = wg >> 1;
    const int nb2 = wg & 1;

    const int r0 = t >> 3;
    const int gsl = (t & 7) ^ (r0 & 7);      // xor-swizzled global chunk
    int row0 = mtile * BM + r0;        if (row0 >= NN) row0 = NN - 1;
    int row1 = mtile * BM + 64 + r0;   if (row1 >= NN) row1 = NN - 1;
    const bf16_t* gA0 = xb + (size_t)row0 * HD + gsl * 8;
    const bf16_t* gA1 = xb + (size_t)row1 * HD + gsl * 8;

    auto stageA = [&](int ks, char* Ab) {
        gl2lds16(gA0 + ks * BK, (bf16_t*)Ab + t * 8);
        gl2lds16(gA1 + ks * BK, (bf16_t*)Ab + 4096 + t * 8);
    };

    f32x4 acc[4][4];
    #pragma unroll
    for (int a_ = 0; a_ < 4; ++a_)
        #pragma unroll
        for (int b_ = 0; b_ < 4; ++b_) acc[a_][b_] = (f32x4){0.f, 0.f, 0.f, 0.f};

    const bf16_t* w1base = w1s + (size_t)nb2 * KST * 16384;

    stageA(0, smem);

    for (int ks = 0; ks < KST; ++ks) {
        bf16_t* Ac = (bf16_t*)(smem + ((ks & 1) << 14));
        char*   An = smem + ((~ks & 1) << 14);
        bf16_t* Bl = (bf16_t*)(smem + 32768);

        __syncthreads();   // B1: drains A(ks); prev-step LDS reads done

        // stage B(ks): 4 gl2lds/thread, lane-linear, coalesced
        #pragma unroll
        for (int i = 0; i < 4; ++i) {
            const int ci = i * 512 + t;
            gl2lds16(w1base + (size_t)ks * 16384 + (size_t)ci * 8, Bl + ci * 8);
        }
        // prefetch A(ks+1); stays in flight across the MFMA phase
        const bool pf = (ks + 1 < KST);
        if (pf) stageA(ks + 1, An);

        // B2: wait only the 4 B gl2lds (issued first -> vmcnt(2) leaves A flying)
        if (pf) asm volatile("s_waitcnt vmcnt(2)\n\ts_barrier" ::: "memory");
        else    asm volatile("s_waitcnt vmcnt(0)\n\ts_barrier" ::: "memory");

        #pragma unroll
        for (int kk = 0; kk < 2; ++kk) {
            bf16x8 af[4];
            const int sl = (kk * 4 + q) ^ (r & 7);
            #pragma unroll
            for (int mb = 0; mb < 4; ++mb)
                af[mb] = *(const bf16x8*)(Ac + (wm * 64 + mb * 16 + r) * 64 + sl * 8);
            #pragma unroll
            for (int nb = 0; nb < 4; ++nb) {
                bf16x8 bfr = *(const bf16x8*)(Bl + (size_t)(((kk * 4 + q) << 8) + wn * 64 + nb * 16 + r) * 8);
                #pragma unroll
                for (int mb = 0; mb < 4; ++mb)
                    acc[mb][nb] = __builtin_amdgcn_mfma_f32_16x16x32_bf16(af[mb], bfr, acc[mb][nb], 0, 0, 0);
            }
        }
    }

    // epilogue: permuted f16x4 stores (8B/lane, coalesced per q-group)
    #pragma unroll
    for (int mb = 0; mb < 4; ++mb) {
        #pragma unroll
        for (int rr = 0; rr < 4; ++rr) {
            const int grow = mtile * BM + wm * 64 + mb * 16 + q * 4 + rr;
            if (grow < NN) {
                f16x4 o;
                #pragma unroll
                for (int nb = 0; nb < 4; ++nb) o[nb] = (f16_t)acc[mb][nb][rr];
                *(f16x4*)(h + (size_t)grow * NOUT + nb2 * DD1 + wn * 64 + r * 4) = o;
            }
        }
    }
}

// ---- edge pass: 1 edge / 8-lane group, 8 named gathers (no arrays -> no scratch) ----
__global__ __launch_bounds__(256, 2)
void edge_mlp5(const f16_t* __restrict__ h, const float* __restrict__ pw,
               const float* __restrict__ b2, const float* __restrict__ cw,
               const int* __restrict__ esrc, const int* __restrict__ edst,
               const int* __restrict__ lab, float* __restrict__ out,
               float* __restrict__ accum)
{
    __shared__ float lds_pw[768];
    __shared__ float red[8];
    const int t = threadIdx.x;
    const int lane = t & 63;
    const int wv = t >> 6;          // 0..3
    const int slot = t >> 3;        // 0..31 (edge within block)
    const int p = t & 7;            // 8 lanes per edge

    for (int i = t; i < 768; i += 256) lds_pw[i] = pw[i];

    const int e = blockIdx.x * 32 + slot;     // 6250 * 32 = NE exactly
    const int src = esrc[e];
    const int dst = edst[e];
    const f16_t* sp = h + (size_t)src * NOUT + p * 8;
    const f16_t* dp = h + (size_t)dst * NOUT + DD1 + p * 8;

    // 8 independent 16B gathers, named (keeps them in VGPRs, lets compiler pipeline)
    f16x8 a0 = *(const f16x8*)(sp);
    f16x8 a1 = *(const f16x8*)(sp + 64);
    f16x8 a2 = *(const f16x8*)(sp + 128);
    f16x8 a3 = *(const f16x8*)(sp + 192);
    f16x8 b0 = *(const f16x8*)(dp);
    f16x8 b1v = *(const f16x8*)(dp + 64);
    f16x8 b2v = *(const f16x8*)(dp + 128);
    f16x8 b3v = *(const f16x8*)(dp + 192);

    __syncthreads();   // lds_pw ready

    float l0 = 0.f, l1 = 0.f;
#define EDGE_GROUP(ha, hb, g)                                              \
    {                                                                      \
        const int c0 = (g) * 64 + p * 8;                                   \
        float4 ba = *(const float4*)(&lds_pw[c0]);                         \
        float4 bb = *(const float4*)(&lds_pw[c0 + 4]);                     \
        float4 wa = *(const float4*)(&lds_pw[256 + c0]);                   \
        float4 wb = *(const float4*)(&lds_pw[256 + c0 + 4]);               \
        float4 va = *(const float4*)(&lds_pw[512 + c0]);                   \
        float4 vb = *(const float4*)(&lds_pw[512 + c0 + 4]);               \
        float v, gl;                                                       \
        v = (float)ha[0] + (float)hb[0] + ba.x;                            \
        gl = 0.5f * v * (1.f + erff(v * 0.70710678118654752f));            \
        l0 += gl * wa.x; l1 += gl * va.x;                                  \
        v = (float)ha[1] + (float)hb[1] + ba.y;                            \
        gl = 0.5f * v * (1.f + erff(v * 0.70710678118654752f));            \
        l0 += gl * wa.y; l1 += gl * va.y;                                  \
        v = (float)ha[2] + (float)hb[2] + ba.z;                            \
        gl = 0.5f * v * (1.f + erff(v * 0.70710678118654752f));            \
        l0 += gl * wa.z; l1 += gl * va.z;                                  \
        v = (float)ha[3] + (float)hb[3] + ba.w;                            \
        gl = 0.5f * v * (1.f + erff(v * 0.70710678118654752f));            \
        l0 += gl * wa.w; l1 += gl * va.w;                                  \
        v = (float)ha[4] + (float)hb[4] + bb.x;                            \
        gl = 0.5f * v * (1.f + erff(v * 0.70710678118654752f));            \
        l0 += gl * wb.x; l1 += gl * vb.x;                                  \
        v = (float)ha[5] + (float)hb[5] + bb.y;                            \
        gl = 0.5f * v * (1.f + erff(v * 0.70710678118654752f));            \
        l0 += gl * wb.y; l1 += gl * vb.y;                                  \
        v = (float)ha[6] + (float)hb[6] + bb.z;                            \
        gl = 0.5f * v * (1.f + erff(v * 0.70710678118654752f));            \
        l0 += gl * wb.z; l1 += gl * vb.z;                                  \
        v = (float)ha[7] + (float)hb[7] + bb.w;                            \
        gl = 0.5f * v * (1.f + erff(v * 0.70710678118654752f));            \
        l0 += gl * wb.w; l1 += gl * vb.w;                                  \
    }

    EDGE_GROUP(a0, b0, 0)
    EDGE_GROUP(a1, b1v, 1)
    EDGE_GROUP(a2, b2v, 2)
    EDGE_GROUP(a3, b3v, 3)
#undef EDGE_GROUP

    l0 += __shfl_xor(l0, 1); l0 += __shfl_xor(l0, 2); l0 += __shfl_xor(l0, 4);
    l1 += __shfl_xor(l1, 1); l1 += __shfl_xor(l1, 2); l1 += __shfl_xor(l1, 4);

    float wnll_t = 0.f, wsum_t = 0.f;
    if (p == 0) {
        float L0 = l0 + b2[0], L1 = l1 + b2[1];
        float mx = fmaxf(L0, L1);
        float ex0 = expf(L0 - mx), ex1 = expf(L1 - mx);
        float s = ex0 + ex1, inv = 1.f / s;
        out[1 + 2 * e] = ex0 * inv;
        out[2 + 2 * e] = ex1 * inv;
        int lb = lab[e];
        float w = cw[lb];
        wnll_t = w * (mx + logf(s) - (lb ? L1 : L0));
        wsum_t = w;
    }
    // reduce over p==0 lanes (0,8,..,56), then cross-wave
    wnll_t += __shfl_xor(wnll_t, 8);  wsum_t += __shfl_xor(wsum_t, 8);
    wnll_t += __shfl_xor(wnll_t, 16); wsum_t += __shfl_xor(wsum_t, 16);
    wnll_t += __shfl_xor(wnll_t, 32); wsum_t += __shfl_xor(wsum_t, 32);
    if (lane == 0) { red[wv] = wnll_t; red[4 + wv] = wsum_t; }
    __syncthreads();
    if (t == 0) {
        float a_ = red[0] + red[1] + red[2] + red[3];
        float b_ = red[4] + red[5] + red[6] + red[7];
        atomicAdd(&accum[0], a_);
        atomicAdd(&accum[1], b_);
    }
}

// ================== round-0 proven fused kernel (tiers 2/3) ==================
template<bool XPRE, bool WPRE>
__global__ __launch_bounds__(512, 4)
void fused_edge_mlp(const float* __restrict__ xf, const bf16_t* __restrict__ xb,
                    const float* __restrict__ w1f, const bf16_t* __restrict__ w1s,
                    const float* __restrict__ b1, const float* __restrict__ w2,
                    const float* __restrict__ b2, const float* __restrict__ cw,
                    const int* __restrict__ esrc, const int* __restrict__ edst,
                    const int* __restrict__ lab, float* __restrict__ out,
                    float* __restrict__ accum)
{
    __shared__ __align__(16) char smem[65536];
    const int t = threadIdx.x;
    const int lane = t & 63;
    const int wv = t >> 6;
    const int wm = wv & 1;
    const int wn = wv >> 1;
    const int q = lane >> 4;
    const int r = lane & 15;
    const int ebase = blockIdx.x * BM;
    const int r0 = t >> 3;
    const int e1c = (ebase + r0 + 64 < NE) ? (ebase + r0 + 64) : 0;
    const int ns0 = esrc[ebase + r0];
    const int nd0 = edst[ebase + r0];
    const int ns1 = esrc[e1c];
    const int nd1 = edst[e1c];
    const int gsl = (t & 7) ^ (r0 & 7);

    f32x4 acc[4][4];
    #pragma unroll
    for (int a_ = 0; a_ < 4; ++a_)
        #pragma unroll
        for (int b_ = 0; b_ < 4; ++b_) acc[a_][b_] = (f32x4){0.f, 0.f, 0.f, 0.f};

    auto stageA = [&](int kp, char* AbBase) {
        const bool issrc = (kp < 12);
        const int col0 = issrc ? kp * BK : kp * BK - HD;
        #pragma unroll
        for (int i = 0; i < 2; ++i) {
            const int node = i ? (issrc ? ns1 : nd1) : (issrc ? ns0 : nd0);
            bf16_t* lp = (bf16_t*)AbBase + i * 4096 + t * 8;
            if (XPRE) {
                gl2lds16(xb + (size_t)node * HD + col0 + gsl * 8, lp);
            } else {
                const float* gp = xf + (size_t)node * HD + col0 + gsl * 8;
                float4 v0 = ((const float4*)gp)[0];
                float4 v1 = ((const float4*)gp)[1];
                bf16x8 o;
                o[0]=(bf16_t)v0.x; o[1]=(bf16_t)v0.y; o[2]=(bf16_t)v0.z; o[3]=(bf16_t)v0.w;
                o[4]=(bf16_t)v1.x; o[5]=(bf16_t)v1.y; o[6]=(bf16_t)v1.z; o[7]=(bf16_t)v1.w;
                *(bf16x8*)lp = o;
            }
        }
    };

    stageA(0, smem);

    for (int ks = 0; ks < KSTEPS; ++ks) {
        bf16_t* Ac = (bf16_t*)(smem + ((ks & 1) << 14));
        char*   An = smem + ((~ks & 1) << 14);
        bf16_t* Bl = (bf16_t*)(smem + 32768);
        __syncthreads();
        #pragma unroll
        for (int i = 0; i < 4; ++i) {
            const int ci = i * 512 + t;
            bf16_t* lp = Bl + ci * 8;
            if (WPRE) {
                gl2lds16(w1s + (size_t)ks * 16384 + ci * 8, lp);
            } else {
                const int n = ci & 255, kc = ci >> 8;
                const float* gp = w1f + (size_t)n * TWOH + ks * BK + kc * 8;
                float4 v0 = ((const float4*)gp)[0];
                float4 v1 = ((const float4*)gp)[1];
                bf16x8 o;
                o[0]=(bf16_t)v0.x; o[1]=(bf16_t)v0.y; o[2]=(bf16_t)v0.z; o[3]=(bf16_t)v0.w;
                o[4]=(bf16_t)v1.x; o[5]=(bf16_t)v1.y; o[6]=(bf16_t)v1.z; o[7]=(bf16_t)v1.w;
                *(bf16x8*)lp = o;
            }
        }
        if (XPRE && WPRE)
            asm volatile("s_waitcnt vmcnt(0)\n\ts_barrier" ::: "memory");
        else
            __syncthreads();
        if (ks + 1 < KSTEPS) stageA(ks + 1, An);
        #pragma unroll
        for (int kk = 0; kk < 2; ++kk) {
            bf16x8 af[4];
            const int sl = (kk * 4 + q) ^ (r & 7);
            #pragma unroll
            for (int mb = 0; mb < 4; ++mb) {
                const int m = wm * 64 + mb * 16 + r;
                af[mb] = *(const bf16x8*)(Ac + m * 64 + sl * 8);
            }
            #pragma unroll
            for (int nb = 0; nb < 4; ++nb) {
                bf16x8 bfr = *(const bf16x8*)(Bl + (size_t)(((kk * 4 + q) << 8) + wn * 64 + nb * 16 + r) * 8);
                #pragma unroll
                for (int mb = 0; mb < 4; ++mb)
                    acc[mb][nb] = __builtin_amdgcn_mfma_f32_16x16x32_bf16(af[mb], bfr, acc[mb][nb], 0, 0, 0);
            }
        }
    }

    bf16_t* Hl = (bf16_t*)smem;
    float* red = (float*)(smem + 32768);
    float bias[4];
    #pragma unroll
    for (int nb = 0; nb < 4; ++nb) bias[nb] = b1[wn * 64 + nb * 16 + r];

    float wnll_t = 0.f, wsum_t = 0.f;
    const int ml2 = t >> 3;
    const int p = t & 7;

    #pragma unroll
    for (int half = 0; half < 2; ++half) {
        __syncthreads();
        if (wm == half) {
            #pragma unroll
            for (int mb = 0; mb < 4; ++mb)
                #pragma unroll
                for (int nb = 0; nb < 4; ++nb)
                    #pragma unroll
                    for (int rr = 0; rr < 4; ++rr) {
                        int ml = mb * 16 + q * 4 + rr;
                        int col = wn * 64 + nb * 16 + r;
                        float v = acc[mb][nb][rr] + bias[nb];
                        float g = 0.5f * v * (1.f + erff(v * 0.70710678118654752f));
                        int swcol = ((((col >> 3) ^ (ml & 7)) << 3) | (col & 7));
                        Hl[ml * 256 + swcol] = (bf16_t)g;
                    }
        }
        __syncthreads();
        float l0 = 0.f, l1 = 0.f;
        #pragma unroll
        for (int j = 0; j < 4; ++j) {
            int cj = p * 4 + j;
            bf16x8 hv = *(const bf16x8*)(Hl + ml2 * 256 + ((cj ^ (ml2 & 7)) << 3));
            const float4* w2a = (const float4*)(w2 + cj * 8);
            const float4* w2b = (const float4*)(w2 + 256 + cj * 8);
            float4 wa0 = w2a[0], wa1 = w2a[1], wb0 = w2b[0], wb1 = w2b[1];
            float hf[8];
            #pragma unroll
            for (int u = 0; u < 8; ++u) hf[u] = (float)hv[u];
            l0 += hf[0]*wa0.x + hf[1]*wa0.y + hf[2]*wa0.z + hf[3]*wa0.w
                + hf[4]*wa1.x + hf[5]*wa1.y + hf[6]*wa1.z + hf[7]*wa1.w;
            l1 += hf[0]*wb0.x + hf[1]*wb0.y + hf[2]*wb0.z + hf[3]*wb0.w
                + hf[4]*wb1.x + hf[5]*wb1.y + hf[6]*wb1.z + hf[7]*wb1.w;
        }
        l0 += __shfl_xor(l0, 1); l0 += __shfl_xor(l0, 2); l0 += __shfl_xor(l0, 4);
        l1 += __shfl_xor(l1, 1); l1 += __shfl_xor(l1, 2); l1 += __shfl_xor(l1, 4);
        const int eg = ebase + half * 64 + ml2;
        if (p == 0 && eg < NE) {
            l0 += b2[0]; l1 += b2[1];
            float mx = fmaxf(l0, l1);
            float e0 = expf(l0 - mx), e1 = expf(l1 - mx);
            float s = e0 + e1;
            float inv = 1.f / s;
            out[1 + 2 * eg] = e0 * inv;
            out[2 + 2 * eg] = e1 * inv;
            int lb = lab[eg];
            float w = cw[lb];
            float lpv = ((lb ? l1 : l0) - mx) - logf(s);
            wnll_t -= w * lpv;
            wsum_t += w;
        }
    }
    #pragma unroll
    for (int o = 1; o < 64; o <<= 1) {
        wnll_t += __shfl_xor(wnll_t, o);
        wsum_t += __shfl_xor(wsum_t, o);
    }
    __syncthreads();
    if (lane == 0) { red[wv] = wnll_t; red[8 + wv] = wsum_t; }
    __syncthreads();
    if (t == 0) {
        float a_ = 0.f, b_ = 0.f;
        #pragma unroll
        for (int i = 0; i < 8; ++i) { a_ += red[i]; b_ += red[8 + i]; }
        atomicAdd(&accum[0], a_);
        atomicAdd(&accum[1], b_);
    }
}

extern "C" void kernel_launch(void* const* d_in, const int* in_sizes, int n_in,
                              void* d_out, int out_size, void* d_ws, size_t ws_size,
                              hipStream_t stream)
{
    (void)in_sizes; (void)n_in; (void)out_size;
    const float* x  = (const float*)d_in[0];
    const float* W1 = (const float*)d_in[1];
    const float* b1 = (const float*)d_in[2];
    const float* W2 = (const float*)d_in[3];
    const float* b2 = (const float*)d_in[4];
    const float* cw = (const float*)d_in[5];
    const int* esrc = (const int*)d_in[6];
    const int* edst = (const int*)d_in[7];
    const int* lab  = (const int*)d_in[8];
    float* out = (float*)d_out;
    char* ws = (char*)d_ws;

    float* accum = (float*)ws;
    const size_t off_w1 = 256;
    const size_t w1s_bytes = (size_t)DD1 * TWOH * 2;     // 786432
    const size_t off_pw = off_w1 + w1s_bytes;            // 786688
    const size_t off_h  = off_pw + 3072;                 // 789760
    const size_t h_bytes = (size_t)NN * NOUT * 2;        // 51.2 MB
    const size_t off_xb = off_h + h_bytes;               // ~52.0 MB
    const size_t xb_bytes = (size_t)NN * HD * 2;         // 76.8 MB
    const size_t off_xb2 = off_h;                        // tier-2: xb where h would be

    (void)hipMemsetAsync(accum, 0, 2 * sizeof(float), stream);

    if (ws_size >= off_xb + xb_bytes) {
        // tier 1: prep (fused) -> node GEMM -> edge pass
        bf16_t* w1s = (bf16_t*)(ws + off_w1);
        float* pw = (float*)(ws + off_pw);
        f16_t* h = (f16_t*)(ws + off_h);
        bf16_t* xb = (bf16_t*)(ws + off_xb);
        prep_all<<<NB_CVT + NB_SWZ + 1, 256, 0, stream>>>(x, xb, W1, w1s, b1, W2, pw);
        node_gemm3<<<391 * 2, 512, 0, stream>>>(xb, w1s, h);
        edge_mlp5<<<NE / 32, 256, 0, stream>>>(h, pw, b2, cw, esrc, edst, lab, out, accum);
    } else if (ws_size >= off_xb2 + xb_bytes) {
        // tier 2: round-0 proven fused path
        bf16_t* w1s = (bf16_t*)(ws + off_w1);
        float* pw = (float*)(ws + off_pw);
        bf16_t* xb = (bf16_t*)(ws + off_xb2);
        prep_all<<<NB_CVT + NB_SWZ + 1, 256, 0, stream>>>(x, xb, W1, w1s, b1, W2, pw);
        dim3 grid((NE + BM - 1) / BM);
        fused_edge_mlp<true, true><<<grid, 512, 0, stream>>>(
            x, xb, W1, w1s, b1, W2, b2, cw, esrc, edst, lab, out, accum);
    } else {
        dim3 grid((NE + BM - 1) / BM);
        fused_edge_mlp<false, false><<<grid, 512, 0, stream>>>(
            x, (const bf16_t*)ws, W1, (const bf16_t*)ws, b1, W2, b2, cw,
            esrc, edst, lab, out, accum);
    }

    finalize_kernel<<<1, 1, 0, stream>>>(out, accum);
}

// Round 5
// 336.336 us; speedup vs baseline: 2.2400x; 1.3506x over previous
//
#include <hip/hip_runtime.h>
#include <math.h>
#include <stdint.h>

#define NN 50000
#define NE 200000
#define HD 768
#define TWOH 1536
#define DD1 256
#define NOUT 512
#define BM 128
#define BK 64
#define KST 12      // node GEMM k-steps (HD/BK)
#define KSTEPS 24   // fused fallback k-steps (TWOH/BK)

#define NB_CVT 9375            // NN*HD/16/256
#define NB_SWZ 192             // KSTEPS*8*256/256

#define EPB 10                 // edges per 8-lane group (pipelined)
#define EBLK (EPB * 32)        // 320 edges per block ; 625 blocks exact

typedef __bf16 bf16_t;
typedef _Float16 f16_t;
typedef __attribute__((ext_vector_type(8))) __bf16 bf16x8;
typedef __attribute__((ext_vector_type(8))) _Float16 f16x8;
typedef __attribute__((ext_vector_type(4))) _Float16 f16x4;
typedef __attribute__((ext_vector_type(4))) float f32x4;

__device__ __forceinline__ void gl2lds16(const void* g, void* l) {
    __builtin_amdgcn_global_load_lds(
        (const __attribute__((address_space(1))) unsigned int*)g,
        (__attribute__((address_space(3))) unsigned int*)l,
        16, 0, 0);
}

// Branchless exact-erf gelu: Abramowitz-Stegun 7.1.26, |eps| <= 1.5e-7.
__device__ __forceinline__ float gelu_erf(float v) {
    float xa = fabsf(v) * 0.70710678118654752f;
    float t  = __builtin_amdgcn_rcpf(fmaf(0.3275911f, xa, 1.0f));
    float pl = fmaf(fmaf(fmaf(fmaf(1.061405429f, t, -1.453152027f), t,
                   1.421413741f), t, -0.284496736f), t, 0.254829592f) * t;
    float er = fmaf(-pl, __expf(-xa * xa), 1.0f);
    er = copysignf(er, v);
    return 0.5f * v * (1.0f + er);
}

// ---- fused prep: [0,NB_CVT) x->bf16 ; [NB_CVT,NB_CVT+NB_SWZ) W1 swizzle ; last block pw ----
__global__ void prep_all(const float* __restrict__ x, bf16_t* __restrict__ xb,
                         const float* __restrict__ w1, bf16_t* __restrict__ w1s,
                         const float* __restrict__ b1, const float* __restrict__ w2,
                         float* __restrict__ pw)
{
    const int b = blockIdx.x;
    const int t = threadIdx.x;
    if (b < NB_CVT) {
        const int i = b * 256 + t;
        const float4* p = (const float4*)x + (size_t)i * 4;
        float4 a = p[0], bq = p[1], c = p[2], d = p[3];
        bf16x8 o0, o1;
        o0[0]=(bf16_t)a.x; o0[1]=(bf16_t)a.y; o0[2]=(bf16_t)a.z; o0[3]=(bf16_t)a.w;
        o0[4]=(bf16_t)bq.x; o0[5]=(bf16_t)bq.y; o0[6]=(bf16_t)bq.z; o0[7]=(bf16_t)bq.w;
        o1[0]=(bf16_t)c.x; o1[1]=(bf16_t)c.y; o1[2]=(bf16_t)c.z; o1[3]=(bf16_t)c.w;
        o1[4]=(bf16_t)d.x; o1[5]=(bf16_t)d.y; o1[6]=(bf16_t)d.z; o1[7]=(bf16_t)d.w;
        bf16x8* q = (bf16x8*)(xb + (size_t)i * 16);
        q[0] = o0; q[1] = o1;
    } else if (b < NB_CVT + NB_SWZ) {
        const int idx = (b - NB_CVT) * 256 + t;
        const int n  = idx & 255;
        const int kc = (idx >> 8) & 7;
        const int ks = idx >> 11;
        const float* gp = w1 + (size_t)n * TWOH + ks * BK + kc * 8;
        float4 v0 = ((const float4*)gp)[0];
        float4 v1 = ((const float4*)gp)[1];
        bf16x8 o;
        o[0]=(bf16_t)v0.x; o[1]=(bf16_t)v0.y; o[2]=(bf16_t)v0.z; o[3]=(bf16_t)v0.w;
        o[4]=(bf16_t)v1.x; o[5]=(bf16_t)v1.y; o[6]=(bf16_t)v1.z; o[7]=(bf16_t)v1.w;
        *(bf16x8*)(w1s + (size_t)idx * 8) = o;
    } else {
        const int s = t;
        const int k = s & 63;
        const int c = (s & 192) + ((k & 3) << 4) + (k >> 2);
        pw[s]       = b1[c];
        pw[256 + s] = w2[c];
        pw[512 + s] = w2[DD1 + c];
    }
}

__global__ void finalize_kernel(float* __restrict__ out, const float* __restrict__ accum) {
    out[0] = accum[0] / accum[1];
}

// ---- node projection GEMM (proven): h[n][perm] = x[n] @ W1^T, raw f16 ----
__global__ __launch_bounds__(512, 4)
void node_gemm3(const bf16_t* __restrict__ xb, const bf16_t* __restrict__ w1s,
                f16_t* __restrict__ h)
{
    __shared__ __align__(16) char smem[65536];

    const int t = threadIdx.x;
    const int lane = t & 63;
    const int wv = t >> 6;
    const int wm = wv & 1;
    const int wn = wv >> 1;
    const int q = lane >> 4;
    const int r = lane & 15;

    const int nwg = 391 * 2;
    const int qq = nwg >> 3, rr8 = nwg & 7;
    int bid = blockIdx.x;
    int xcd = bid & 7, ii = bid >> 3;
    int wg = (xcd < rr8 ? xcd * (qq + 1) : rr8 * (qq + 1) + (xcd - rr8) * qq) + ii;
    const int mtile = wg >> 1;
    const int nb2 = wg & 1;

    const int r0 = t >> 3;
    const int gsl = (t & 7) ^ (r0 & 7);
    int row0 = mtile * BM + r0;        if (row0 >= NN) row0 = NN - 1;
    int row1 = mtile * BM + 64 + r0;   if (row1 >= NN) row1 = NN - 1;
    const bf16_t* gA0 = xb + (size_t)row0 * HD + gsl * 8;
    const bf16_t* gA1 = xb + (size_t)row1 * HD + gsl * 8;

    auto stageA = [&](int ks, char* Ab) {
        gl2lds16(gA0 + ks * BK, (bf16_t*)Ab + t * 8);
        gl2lds16(gA1 + ks * BK, (bf16_t*)Ab + 4096 + t * 8);
    };

    f32x4 acc[4][4];
    #pragma unroll
    for (int a_ = 0; a_ < 4; ++a_)
        #pragma unroll
        for (int b_ = 0; b_ < 4; ++b_) acc[a_][b_] = (f32x4){0.f, 0.f, 0.f, 0.f};

    const bf16_t* w1base = w1s + (size_t)nb2 * KST * 16384;

    stageA(0, smem);

    for (int ks = 0; ks < KST; ++ks) {
        bf16_t* Ac = (bf16_t*)(smem + ((ks & 1) << 14));
        char*   An = smem + ((~ks & 1) << 14);
        bf16_t* Bl = (bf16_t*)(smem + 32768);

        __syncthreads();

        #pragma unroll
        for (int i = 0; i < 4; ++i) {
            const int ci = i * 512 + t;
            gl2lds16(w1base + (size_t)ks * 16384 + (size_t)ci * 8, Bl + ci * 8);
        }
        const bool pf = (ks + 1 < KST);
        if (pf) stageA(ks + 1, An);

        if (pf) asm volatile("s_waitcnt vmcnt(2)\n\ts_barrier" ::: "memory");
        else    asm volatile("s_waitcnt vmcnt(0)\n\ts_barrier" ::: "memory");

        #pragma unroll
        for (int kk = 0; kk < 2; ++kk) {
            bf16x8 af[4];
            const int sl = (kk * 4 + q) ^ (r & 7);
            #pragma unroll
            for (int mb = 0; mb < 4; ++mb)
                af[mb] = *(const bf16x8*)(Ac + (wm * 64 + mb * 16 + r) * 64 + sl * 8);
            #pragma unroll
            for (int nb = 0; nb < 4; ++nb) {
                bf16x8 bfr = *(const bf16x8*)(Bl + (size_t)(((kk * 4 + q) << 8) + wn * 64 + nb * 16 + r) * 8);
                #pragma unroll
                for (int mb = 0; mb < 4; ++mb)
                    acc[mb][nb] = __builtin_amdgcn_mfma_f32_16x16x32_bf16(af[mb], bfr, acc[mb][nb], 0, 0, 0);
            }
        }
    }

    #pragma unroll
    for (int mb = 0; mb < 4; ++mb) {
        #pragma unroll
        for (int rr = 0; rr < 4; ++rr) {
            const int grow = mtile * BM + wm * 64 + mb * 16 + q * 4 + rr;
            if (grow < NN) {
                f16x4 o;
                #pragma unroll
                for (int nb = 0; nb < 4; ++nb) o[nb] = (f16_t)acc[mb][nb][rr];
                *(f16x4*)(h + (size_t)grow * NOUT + nb2 * DD1 + wn * 64 + r * 4) = o;
            }
        }
    }
}

// ---- per-edge compute on register-resident h fragments ----
__device__ __forceinline__ void edge_compute(
    f16x8 a0, f16x8 a1, f16x8 a2, f16x8 a3,
    f16x8 c0v, f16x8 c1v, f16x8 c2v, f16x8 c3v,
    int e, int lb, int p, const float* lds_pw,
    float b20, float b21, float cw0, float cw1,
    float* __restrict__ out, float& wnll_t, float& wsum_t)
{
    float l0 = 0.f, l1 = 0.f;
#define GRP(ha, hb, g) { \
        const int c0_ = (g) * 64 + p * 8; \
        float4 ba = *(const float4*)(&lds_pw[c0_]); \
        float4 bb = *(const float4*)(&lds_pw[c0_ + 4]); \
        float4 wa = *(const float4*)(&lds_pw[256 + c0_]); \
        float4 wb = *(const float4*)(&lds_pw[256 + c0_ + 4]); \
        float4 va = *(const float4*)(&lds_pw[512 + c0_]); \
        float4 vb = *(const float4*)(&lds_pw[512 + c0_ + 4]); \
        float gl; \
        gl = gelu_erf((float)ha[0] + (float)hb[0] + ba.x); l0 = fmaf(gl, wa.x, l0); l1 = fmaf(gl, va.x, l1); \
        gl = gelu_erf((float)ha[1] + (float)hb[1] + ba.y); l0 = fmaf(gl, wa.y, l0); l1 = fmaf(gl, va.y, l1); \
        gl = gelu_erf((float)ha[2] + (float)hb[2] + ba.z); l0 = fmaf(gl, wa.z, l0); l1 = fmaf(gl, va.z, l1); \
        gl = gelu_erf((float)ha[3] + (float)hb[3] + ba.w); l0 = fmaf(gl, wa.w, l0); l1 = fmaf(gl, va.w, l1); \
        gl = gelu_erf((float)ha[4] + (float)hb[4] + bb.x); l0 = fmaf(gl, wb.x, l0); l1 = fmaf(gl, vb.x, l1); \
        gl = gelu_erf((float)ha[5] + (float)hb[5] + bb.y); l0 = fmaf(gl, wb.y, l0); l1 = fmaf(gl, vb.y, l1); \
        gl = gelu_erf((float)ha[6] + (float)hb[6] + bb.z); l0 = fmaf(gl, wb.z, l0); l1 = fmaf(gl, vb.z, l1); \
        gl = gelu_erf((float)ha[7] + (float)hb[7] + bb.w); l0 = fmaf(gl, wb.w, l0); l1 = fmaf(gl, vb.w, l1); \
    }
    GRP(a0, c0v, 0)
    GRP(a1, c1v, 1)
    GRP(a2, c2v, 2)
    GRP(a3, c3v, 3)
#undef GRP
    l0 += __shfl_xor(l0, 1); l0 += __shfl_xor(l0, 2); l0 += __shfl_xor(l0, 4);
    l1 += __shfl_xor(l1, 1); l1 += __shfl_xor(l1, 2); l1 += __shfl_xor(l1, 4);
    if (p == 0) {
        float L0 = l0 + b20, L1 = l1 + b21;
        float mx = fmaxf(L0, L1);
        float ex0 = __expf(L0 - mx), ex1 = __expf(L1 - mx);
        float s = ex0 + ex1, inv = 1.f / s;
        out[1 + 2 * e] = ex0 * inv;
        out[2 + 2 * e] = ex1 * inv;
        float w = lb ? cw1 : cw0;
        wnll_t += w * (mx + logf(s) - (lb ? L1 : L0));
        wsum_t += w;
    }
}

// ---- edge pass: 2-deep register pipeline, 10 edges per 8-lane group ----
__global__ __launch_bounds__(256, 4)
void edge_mlp6(const f16_t* __restrict__ h, const float* __restrict__ pw,
               const float* __restrict__ b2, const float* __restrict__ cw,
               const int* __restrict__ esrc, const int* __restrict__ edst,
               const int* __restrict__ lab, float* __restrict__ out,
               float* __restrict__ accum)
{
    __shared__ float lds_pw[768];
    __shared__ float red[8];
    const int t = threadIdx.x;
    const int lane = t & 63;
    const int wv = t >> 6;          // 0..3
    const int slot = t >> 3;        // 0..31 (group in block)
    const int p = t & 7;            // 8 lanes per edge

    for (int i = t; i < 768; i += 256) lds_pw[i] = pw[i];

    const float b20 = b2[0], b21 = b2[1];
    const float cw0 = cw[0], cw1 = cw[1];
    const int e0i = blockIdx.x * EBLK + slot;   // 625 * 320 = NE exactly

    float wnll_t = 0.f, wsum_t = 0.f;

    int Xe, Xs, Xd, Xlb, Ye, Ys, Yd, Ylb;
    f16x8 Xa0, Xa1, Xa2, Xa3, Xc0, Xc1, Xc2, Xc3;
    f16x8 Ya0, Ya1, Ya2, Ya3, Yc0, Yc1, Yc2, Yc3;

#define META(B, k) { B##e = e0i + (k) * 32; B##s = esrc[B##e]; B##d = edst[B##e]; B##lb = lab[B##e]; }
#define DATA(B) { \
        const f16_t* sp_ = h + (size_t)B##s * NOUT + p * 8; \
        const f16_t* dp_ = h + (size_t)B##d * NOUT + DD1 + p * 8; \
        B##a0 = *(const f16x8*)(sp_);        B##a1 = *(const f16x8*)(sp_ + 64); \
        B##a2 = *(const f16x8*)(sp_ + 128);  B##a3 = *(const f16x8*)(sp_ + 192); \
        B##c0 = *(const f16x8*)(dp_);        B##c1 = *(const f16x8*)(dp_ + 64); \
        B##c2 = *(const f16x8*)(dp_ + 128);  B##c3 = *(const f16x8*)(dp_ + 192); }

    META(X, 0)
    DATA(X)
    META(Y, 1)
    __syncthreads();   // lds_pw ready

    for (int k = 0; k < EPB; k += 2) {
        // issue h-gathers for edge k+1 (meta loaded one phase ago)
        DATA(Y)
        {
            const int eC = Xe, lbC = Xlb;
            if (k + 2 < EPB) META(X, k + 2)          // meta prefetch flies over computeX
            edge_compute(Xa0, Xa1, Xa2, Xa3, Xc0, Xc1, Xc2, Xc3,
                         eC, lbC, p, lds_pw, b20, b21, cw0, cw1, out, wnll_t, wsum_t);
        }
        __builtin_amdgcn_sched_barrier(0);
        if (k + 2 < EPB) DATA(X)                     // gathers fly over computeY
        {
            const int eC = Ye, lbC = Ylb;
            if (k + 3 < EPB) META(Y, k + 3)
            edge_compute(Ya0, Ya1, Ya2, Ya3, Yc0, Yc1, Yc2, Yc3,
                         eC, lbC, p, lds_pw, b20, b21, cw0, cw1, out, wnll_t, wsum_t);
        }
        __builtin_amdgcn_sched_barrier(0);
    }
#undef META
#undef DATA

    // reduce over p==0 lanes (0,8,..,56), then cross-wave
    wnll_t += __shfl_xor(wnll_t, 8);  wsum_t += __shfl_xor(wsum_t, 8);
    wnll_t += __shfl_xor(wnll_t, 16); wsum_t += __shfl_xor(wsum_t, 16);
    wnll_t += __shfl_xor(wnll_t, 32); wsum_t += __shfl_xor(wsum_t, 32);
    if (lane == 0) { red[wv] = wnll_t; red[4 + wv] = wsum_t; }
    __syncthreads();
    if (t == 0) {
        float a_ = red[0] + red[1] + red[2] + red[3];
        float b_ = red[4] + red[5] + red[6] + red[7];
        atomicAdd(&accum[0], a_);
        atomicAdd(&accum[1], b_);
    }
}

// ================== round-0 proven fused kernel (tiers 2/3) ==================
template<bool XPRE, bool WPRE>
__global__ __launch_bounds__(512, 4)
void fused_edge_mlp(const float* __restrict__ xf, const bf16_t* __restrict__ xb,
                    const float* __restrict__ w1f, const bf16_t* __restrict__ w1s,
                    const float* __restrict__ b1, const float* __restrict__ w2,
                    const float* __restrict__ b2, const float* __restrict__ cw,
                    const int* __restrict__ esrc, const int* __restrict__ edst,
                    const int* __restrict__ lab, float* __restrict__ out,
                    float* __restrict__ accum)
{
    __shared__ __align__(16) char smem[65536];
    const int t = threadIdx.x;
    const int lane = t & 63;
    const int wv = t >> 6;
    const int wm = wv & 1;
    const int wn = wv >> 1;
    const int q = lane >> 4;
    const int r = lane & 15;
    const int ebase = blockIdx.x * BM;
    const int r0 = t >> 3;
    const int e1c = (ebase + r0 + 64 < NE) ? (ebase + r0 + 64) : 0;
    const int ns0 = esrc[ebase + r0];
    const int nd0 = edst[ebase + r0];
    const int ns1 = esrc[e1c];
    const int nd1 = edst[e1c];
    const int gsl = (t & 7) ^ (r0 & 7);

    f32x4 acc[4][4];
    #pragma unroll
    for (int a_ = 0; a_ < 4; ++a_)
        #pragma unroll
        for (int b_ = 0; b_ < 4; ++b_) acc[a_][b_] = (f32x4){0.f, 0.f, 0.f, 0.f};

    auto stageA = [&](int kp, char* AbBase) {
        const bool issrc = (kp < 12);
        const int col0 = issrc ? kp * BK : kp * BK - HD;
        #pragma unroll
        for (int i = 0; i < 2; ++i) {
            const int node = i ? (issrc ? ns1 : nd1) : (issrc ? ns0 : nd0);
            bf16_t* lp = (bf16_t*)AbBase + i * 4096 + t * 8;
            if (XPRE) {
                gl2lds16(xb + (size_t)node * HD + col0 + gsl * 8, lp);
            } else {
                const float* gp = xf + (size_t)node * HD + col0 + gsl * 8;
                float4 v0 = ((const float4*)gp)[0];
                float4 v1 = ((const float4*)gp)[1];
                bf16x8 o;
                o[0]=(bf16_t)v0.x; o[1]=(bf16_t)v0.y; o[2]=(bf16_t)v0.z; o[3]=(bf16_t)v0.w;
                o[4]=(bf16_t)v1.x; o[5]=(bf16_t)v1.y; o[6]=(bf16_t)v1.z; o[7]=(bf16_t)v1.w;
                *(bf16x8*)lp = o;
            }
        }
    };

    stageA(0, smem);

    for (int ks = 0; ks < KSTEPS; ++ks) {
        bf16_t* Ac = (bf16_t*)(smem + ((ks & 1) << 14));
        char*   An = smem + ((~ks & 1) << 14);
        bf16_t* Bl = (bf16_t*)(smem + 32768);
        __syncthreads();
        #pragma unroll
        for (int i = 0; i < 4; ++i) {
            const int ci = i * 512 + t;
            bf16_t* lp = Bl + ci * 8;
            if (WPRE) {
                gl2lds16(w1s + (size_t)ks * 16384 + ci * 8, lp);
            } else {
                const int n = ci & 255, kc = ci >> 8;
                const float* gp = w1f + (size_t)n * TWOH + ks * BK + kc * 8;
                float4 v0 = ((const float4*)gp)[0];
                float4 v1 = ((const float4*)gp)[1];
                bf16x8 o;
                o[0]=(bf16_t)v0.x; o[1]=(bf16_t)v0.y; o[2]=(bf16_t)v0.z; o[3]=(bf16_t)v0.w;
                o[4]=(bf16_t)v1.x; o[5]=(bf16_t)v1.y; o[6]=(bf16_t)v1.z; o[7]=(bf16_t)v1.w;
                *(bf16x8*)lp = o;
            }
        }
        if (XPRE && WPRE)
            asm volatile("s_waitcnt vmcnt(0)\n\ts_barrier" ::: "memory");
        else
            __syncthreads();
        if (ks + 1 < KSTEPS) stageA(ks + 1, An);
        #pragma unroll
        for (int kk = 0; kk < 2; ++kk) {
            bf16x8 af[4];
            const int sl = (kk * 4 + q) ^ (r & 7);
            #pragma unroll
            for (int mb = 0; mb < 4; ++mb) {
                const int m = wm * 64 + mb * 16 + r;
                af[mb] = *(const bf16x8*)(Ac + m * 64 + sl * 8);
            }
            #pragma unroll
            for (int nb = 0; nb < 4; ++nb) {
                bf16x8 bfr = *(const bf16x8*)(Bl + (size_t)(((kk * 4 + q) << 8) + wn * 64 + nb * 16 + r) * 8);
                #pragma unroll
                for (int mb = 0; mb < 4; ++mb)
                    acc[mb][nb] = __builtin_amdgcn_mfma_f32_16x16x32_bf16(af[mb], bfr, acc[mb][nb], 0, 0, 0);
            }
        }
    }

    bf16_t* Hl = (bf16_t*)smem;
    float* red = (float*)(smem + 32768);
    float bias[4];
    #pragma unroll
    for (int nb = 0; nb < 4; ++nb) bias[nb] = b1[wn * 64 + nb * 16 + r];

    float wnll_t = 0.f, wsum_t = 0.f;
    const int ml2 = t >> 3;
    const int p = t & 7;

    #pragma unroll
    for (int half = 0; half < 2; ++half) {
        __syncthreads();
        if (wm == half) {
            #pragma unroll
            for (int mb = 0; mb < 4; ++mb)
                #pragma unroll
                for (int nb = 0; nb < 4; ++nb)
                    #pragma unroll
                    for (int rr = 0; rr < 4; ++rr) {
                        int ml = mb * 16 + q * 4 + rr;
                        int col = wn * 64 + nb * 16 + r;
                        float v = acc[mb][nb][rr] + bias[nb];
                        float g = 0.5f * v * (1.f + erff(v * 0.70710678118654752f));
                        int swcol = ((((col >> 3) ^ (ml & 7)) << 3) | (col & 7));
                        Hl[ml * 256 + swcol] = (bf16_t)g;
                    }
        }
        __syncthreads();
        float l0 = 0.f, l1 = 0.f;
        #pragma unroll
        for (int j = 0; j < 4; ++j) {
            int cj = p * 4 + j;
            bf16x8 hv = *(const bf16x8*)(Hl + ml2 * 256 + ((cj ^ (ml2 & 7)) << 3));
            const float4* w2a = (const float4*)(w2 + cj * 8);
            const float4* w2b = (const float4*)(w2 + 256 + cj * 8);
            float4 wa0 = w2a[0], wa1 = w2a[1], wb0 = w2b[0], wb1 = w2b[1];
            float hf[8];
            #pragma unroll
            for (int u = 0; u < 8; ++u) hf[u] = (float)hv[u];
            l0 += hf[0]*wa0.x + hf[1]*wa0.y + hf[2]*wa0.z + hf[3]*wa0.w
                + hf[4]*wa1.x + hf[5]*wa1.y + hf[6]*wa1.z + hf[7]*wa1.w;
            l1 += hf[0]*wb0.x + hf[1]*wb0.y + hf[2]*wb0.z + hf[3]*wb0.w
                + hf[4]*wb1.x + hf[5]*wb1.y + hf[6]*wb1.z + hf[7]*wb1.w;
        }
        l0 += __shfl_xor(l0, 1); l0 += __shfl_xor(l0, 2); l0 += __shfl_xor(l0, 4);
        l1 += __shfl_xor(l1, 1); l1 += __shfl_xor(l1, 2); l1 += __shfl_xor(l1, 4);
        const int eg = ebase + half * 64 + ml2;
        if (p == 0 && eg < NE) {
            l0 += b2[0]; l1 += b2[1];
            float mx = fmaxf(l0, l1);
            float e0 = expf(l0 - mx), e1 = expf(l1 - mx);
            float s = e0 + e1;
            float inv = 1.f / s;
            out[1 + 2 * eg] = e0 * inv;
            out[2 + 2 * eg] = e1 * inv;
            int lb = lab[eg];
            float w = cw[lb];
            float lpv = ((lb ? l1 : l0) - mx) - logf(s);
            wnll_t -= w * lpv;
            wsum_t += w;
        }
    }
    #pragma unroll
    for (int o = 1; o < 64; o <<= 1) {
        wnll_t += __shfl_xor(wnll_t, o);
        wsum_t += __shfl_xor(wsum_t, o);
    }
    __syncthreads();
    if (lane == 0) { red[wv] = wnll_t; red[8 + wv] = wsum_t; }
    __syncthreads();
    if (t == 0) {
        float a_ = 0.f, b_ = 0.f;
        #pragma unroll
        for (int i = 0; i < 8; ++i) { a_ += red[i]; b_ += red[8 + i]; }
        atomicAdd(&accum[0], a_);
        atomicAdd(&accum[1], b_);
    }
}

extern "C" void kernel_launch(void* const* d_in, const int* in_sizes, int n_in,
                              void* d_out, int out_size, void* d_ws, size_t ws_size,
                              hipStream_t stream)
{
    (void)in_sizes; (void)n_in; (void)out_size;
    const float* x  = (const float*)d_in[0];
    const float* W1 = (const float*)d_in[1];
    const float* b1 = (const float*)d_in[2];
    const float* W2 = (const float*)d_in[3];
    const float* b2 = (const float*)d_in[4];
    const float* cw = (const float*)d_in[5];
    const int* esrc = (const int*)d_in[6];
    const int* edst = (const int*)d_in[7];
    const int* lab  = (const int*)d_in[8];
    float* out = (float*)d_out;
    char* ws = (char*)d_ws;

    float* accum = (float*)ws;
    const size_t off_w1 = 256;
    const size_t w1s_bytes = (size_t)DD1 * TWOH * 2;     // 786432
    const size_t off_pw = off_w1 + w1s_bytes;            // 786688
    const size_t off_h  = off_pw + 3072;                 // 789760
    const size_t h_bytes = (size_t)NN * NOUT * 2;        // 51.2 MB
    const size_t off_xb = off_h + h_bytes;               // ~52.0 MB
    const size_t xb_bytes = (size_t)NN * HD * 2;         // 76.8 MB
    const size_t off_xb2 = off_h;                        // tier-2: xb where h would be

    (void)hipMemsetAsync(accum, 0, 2 * sizeof(float), stream);

    if (ws_size >= off_xb + xb_bytes) {
        // tier 1: prep (fused) -> node GEMM -> pipelined edge pass
        bf16_t* w1s = (bf16_t*)(ws + off_w1);
        float* pw = (float*)(ws + off_pw);
        f16_t* h = (f16_t*)(ws + off_h);
        bf16_t* xb = (bf16_t*)(ws + off_xb);
        prep_all<<<NB_CVT + NB_SWZ + 1, 256, 0, stream>>>(x, xb, W1, w1s, b1, W2, pw);
        node_gemm3<<<391 * 2, 512, 0, stream>>>(xb, w1s, h);
        edge_mlp6<<<NE / EBLK, 256, 0, stream>>>(h, pw, b2, cw, esrc, edst, lab, out, accum);
    } else if (ws_size >= off_xb2 + xb_bytes) {
        // tier 2: round-0 proven fused path
        bf16_t* w1s = (bf16_t*)(ws + off_w1);
        float* pw = (float*)(ws + off_pw);
        bf16_t* xb = (bf16_t*)(ws + off_xb2);
        prep_all<<<NB_CVT + NB_SWZ + 1, 256, 0, stream>>>(x, xb, W1, w1s, b1, W2, pw);
        dim3 grid((NE + BM - 1) / BM);
        fused_edge_mlp<true, true><<<grid, 512, 0, stream>>>(
            x, xb, W1, w1s, b1, W2, b2, cw, esrc, edst, lab, out, accum);
    } else {
        dim3 grid((NE + BM - 1) / BM);
        fused_edge_mlp<false, false><<<grid, 512, 0, stream>>>(
            x, (const bf16_t*)ws, W1, (const bf16_t*)ws, b1, W2, b2, cw,
            esrc, edst, lab, out, accum);
    }

    finalize_kernel<<<1, 1, 0, stream>>>(out, accum);
}

// Round 8
// 333.457 us; speedup vs baseline: 2.2593x; 1.0086x over previous
//
#include <hip/hip_runtime.h>
#include <math.h>
#include <stdint.h>

#define NN 50000
#define NE 200000
#define HD 768
#define TWOH 1536
#define DD1 256
#define NOUT 512
#define BM 128
#define BK 64
#define KST 12      // node GEMM k-steps (HD/BK)
#define KSTEPS 24   // fused fallback k-steps (TWOH/BK)

#define NB_SWZ 192             // KSTEPS*8*256/256 (W1 swizzle blocks)

#define EPB 10                 // edges per 8-lane group (pipelined)
#define EBLK (EPB * 32)        // 320 edges per block ; 625 blocks exact

typedef __bf16 bf16_t;
typedef _Float16 f16_t;
typedef __attribute__((ext_vector_type(8))) __bf16 bf16x8;
typedef __attribute__((ext_vector_type(8))) _Float16 f16x8;
typedef __attribute__((ext_vector_type(4))) _Float16 f16x4;
typedef __attribute__((ext_vector_type(4))) float f32x4;

__device__ __forceinline__ void gl2lds16(const void* g, void* l) {
    __builtin_amdgcn_global_load_lds(
        (const __attribute__((address_space(1))) unsigned int*)g,
        (__attribute__((address_space(3))) unsigned int*)l,
        16, 0, 0);
}

// Branchless exact-erf gelu: Abramowitz-Stegun 7.1.26, |eps| <= 1.5e-7.
__device__ __forceinline__ float gelu_erf(float v) {
    float xa = fabsf(v) * 0.70710678118654752f;
    float t  = __builtin_amdgcn_rcpf(fmaf(0.3275911f, xa, 1.0f));
    float pl = fmaf(fmaf(fmaf(fmaf(1.061405429f, t, -1.453152027f), t,
                   1.421413741f), t, -0.284496736f), t, 0.254829592f) * t;
    float er = fmaf(-pl, __expf(-xa * xa), 1.0f);
    er = copysignf(er, v);
    return 0.5f * v * (1.0f + er);
}

// ---- prep: [0,NB_SWZ) W1 f32->bf16 swizzled [ks24][kc][n][8] ; last block pw permute ----
__global__ void prep_w(const float* __restrict__ w1, bf16_t* __restrict__ w1s,
                       const float* __restrict__ b1, const float* __restrict__ w2,
                       float* __restrict__ pw)
{
    const int b = blockIdx.x;
    const int t = threadIdx.x;
    if (b < NB_SWZ) {
        const int idx = b * 256 + t;
        const int n  = idx & 255;
        const int kc = (idx >> 8) & 7;
        const int ks = idx >> 11;          // 0..23 over TWOH
        const float* gp = w1 + (size_t)n * TWOH + ks * BK + kc * 8;
        float4 v0 = ((const float4*)gp)[0];
        float4 v1 = ((const float4*)gp)[1];
        bf16x8 o;
        o[0]=(bf16_t)v0.x; o[1]=(bf16_t)v0.y; o[2]=(bf16_t)v0.z; o[3]=(bf16_t)v0.w;
        o[4]=(bf16_t)v1.x; o[5]=(bf16_t)v1.y; o[6]=(bf16_t)v1.z; o[7]=(bf16_t)v1.w;
        *(bf16x8*)(w1s + (size_t)idx * 8) = o;
    } else {
        // permuted b1/w2: stored s = wn*64 + r*4 + nb  <->  orig c = wn*64 + nb*16 + r
        const int s = t;
        const int k = s & 63;
        const int c = (s & 192) + ((k & 3) << 4) + (k >> 2);
        pw[s]       = b1[c];
        pw[256 + s] = w2[c];
        pw[512 + s] = w2[DD1 + c];
    }
}

__global__ void finalize_kernel(float* __restrict__ out, const float* __restrict__ accum) {
    out[0] = accum[0] / accum[1];
}

// ---- node projection GEMM, A staged f32->reg->cvt->ds_write, plain barriers ONLY ----
// Correct by construction: every LDS hazard is covered by __syncthreads()'s full
// vmcnt(0)+lgkmcnt(0) drain (compiler-emitted). No inline asm, no counted vmcnt.
// h[n][perm(0:256)] = x[n] @ W1a^T ; h[n][perm(256:512)] = x[n] @ W1b^T  (raw, f16)
__global__ __launch_bounds__(512, 4)
void node_gemm5(const float* __restrict__ x, const bf16_t* __restrict__ w1s,
                f16_t* __restrict__ h)
{
    // LDS: A[128m][64k] 16KB @0 | B[8kc][256n][8] 32KB @16384 = 48KB
    __shared__ __align__(16) char smem[49152];

    const int t = threadIdx.x;
    const int lane = t & 63;
    const int wv = t >> 6;
    const int wm = wv & 1;          // m-half
    const int wn = wv >> 1;         // 64-col quarter
    const int q = lane >> 4;
    const int r = lane & 15;

    // bijective XCD-chunked swizzle; nb2 pair of each mtile adjacent -> same XCD L2
    const int nwg = 391 * 2;                 // 782
    const int qq = nwg >> 3, rr8 = nwg & 7;  // 97, 6
    int bid = blockIdx.x;
    int xcd = bid & 7, ii = bid >> 3;
    int wg = (xcd < rr8 ? xcd * (qq + 1) : rr8 * (qq + 1) + (xcd - rr8) * qq) + ii;
    const int mtile = wg >> 1;
    const int nb2 = wg & 1;

    // A staging: thread -> row arow = t>>2 (coalesced 256B/row via 4 threads),
    // f32 cols [achk*16, achk*16+16) = bf16 chunks 2*achk, 2*achk+1
    const int arow = t >> 2;
    const int achk = t & 3;
    int grow = mtile * BM + arow;  if (grow >= NN) grow = NN - 1;
    const float* gA = x + (size_t)grow * HD + achk * 16;

    bf16_t* Al = (bf16_t*)smem;
    bf16_t* Bl = (bf16_t*)(smem + 16384);

    float4 pr[4];
    auto loadA = [&](int ks) {
        const float4* p = (const float4*)(gA + ks * BK);
        pr[0] = p[0]; pr[1] = p[1]; pr[2] = p[2]; pr[3] = p[3];
    };
    // write chunk c at slot c^(arow&7): matches MFMA read sl = chunk^(m&7)
    auto writeA = [&]() {
        bf16x8 o0, o1;
        o0[0]=(bf16_t)pr[0].x; o0[1]=(bf16_t)pr[0].y; o0[2]=(bf16_t)pr[0].z; o0[3]=(bf16_t)pr[0].w;
        o0[4]=(bf16_t)pr[1].x; o0[5]=(bf16_t)pr[1].y; o0[6]=(bf16_t)pr[1].z; o0[7]=(bf16_t)pr[1].w;
        o1[0]=(bf16_t)pr[2].x; o1[1]=(bf16_t)pr[2].y; o1[2]=(bf16_t)pr[2].z; o1[3]=(bf16_t)pr[2].w;
        o1[4]=(bf16_t)pr[3].x; o1[5]=(bf16_t)pr[3].y; o1[6]=(bf16_t)pr[3].z; o1[7]=(bf16_t)pr[3].w;
        const int c0 = achk * 2;
        bf16_t* base = Al + arow * 64;
        *(bf16x8*)(base + ((c0 ^ (arow & 7)) << 3))       = o0;
        *(bf16x8*)(base + (((c0 + 1) ^ (arow & 7)) << 3)) = o1;
    };

    f32x4 acc[4][4];
    #pragma unroll
    for (int a_ = 0; a_ < 4; ++a_)
        #pragma unroll
        for (int b_ = 0; b_ < 4; ++b_) acc[a_][b_] = (f32x4){0.f, 0.f, 0.f, 0.f};

    const bf16_t* w1base = w1s + (size_t)nb2 * KST * 16384;

    loadA(0);   // prefetch A(0) into registers

    for (int ks = 0; ks < KST; ++ks) {
        __syncthreads();   // B1: all waves done reading A/B of step ks-1

        // stage B(ks): 4 gl2lds/thread, lane-linear, coalesced
        #pragma unroll
        for (int i = 0; i < 4; ++i) {
            const int ci = i * 512 + t;
            gl2lds16(w1base + (size_t)ks * 16384 + (size_t)ci * 8, Bl + ci * 8);
        }
        // convert A(ks) (pr, prefetched) -> LDS; then prefetch A(ks+1) into regs
        writeA();
        if (ks + 1 < KST) loadA(ks + 1);

        __syncthreads();   // B2: compiler drains vmcnt(0)+lgkmcnt(0): B landed, A visible

        #pragma unroll
        for (int kk = 0; kk < 2; ++kk) {
            bf16x8 af[4];
            const int sl = (kk * 4 + q) ^ (r & 7);
            #pragma unroll
            for (int mb = 0; mb < 4; ++mb)
                af[mb] = *(const bf16x8*)(Al + (wm * 64 + mb * 16 + r) * 64 + sl * 8);
            #pragma unroll
            for (int nb = 0; nb < 4; ++nb) {
                bf16x8 bfr = *(const bf16x8*)(Bl + (size_t)(((kk * 4 + q) << 8) + wn * 64 + nb * 16 + r) * 8);
                #pragma unroll
                for (int mb = 0; mb < 4; ++mb)
                    acc[mb][nb] = __builtin_amdgcn_mfma_f32_16x16x32_bf16(af[mb], bfr, acc[mb][nb], 0, 0, 0);
            }
        }
    }

    // epilogue: permuted f16x4 stores (8B/lane, coalesced per q-group) — proven layout
    // row = wm*64 + mb*16 + q*4 + rr ; cols s = wn*64 + r*4 + {0..3} (orig c = wn*64+nb*16+r)
    #pragma unroll
    for (int mb = 0; mb < 4; ++mb) {
        #pragma unroll
        for (int rr = 0; rr < 4; ++rr) {
            const int gr2 = mtile * BM + wm * 64 + mb * 16 + q * 4 + rr;
            if (gr2 < NN) {
                f16x4 o;
                #pragma unroll
                for (int nb = 0; nb < 4; ++nb) o[nb] = (f16_t)acc[mb][nb][rr];
                *(f16x4*)(h + (size_t)gr2 * NOUT + nb2 * DD1 + wn * 64 + r * 4) = o;
            }
        }
    }
}

// ---- per-edge compute on register-resident h fragments (proven round-5) ----
__device__ __forceinline__ void edge_compute(
    f16x8 a0, f16x8 a1, f16x8 a2, f16x8 a3,
    f16x8 c0v, f16x8 c1v, f16x8 c2v, f16x8 c3v,
    int e, int lb, int p, const float* lds_pw,
    float b20, float b21, float cw0, float cw1,
    float* __restrict__ out, float& wnll_t, float& wsum_t)
{
    float l0 = 0.f, l1 = 0.f;
#define GRP(ha, hb, g) { \
        const int c0_ = (g) * 64 + p * 8; \
        float4 ba = *(const float4*)(&lds_pw[c0_]); \
        float4 bb = *(const float4*)(&lds_pw[c0_ + 4]); \
        float4 wa = *(const float4*)(&lds_pw[256 + c0_]); \
        float4 wb = *(const float4*)(&lds_pw[256 + c0_ + 4]); \
        float4 va = *(const float4*)(&lds_pw[512 + c0_]); \
        float4 vb = *(const float4*)(&lds_pw[512 + c0_ + 4]); \
        float gl; \
        gl = gelu_erf((float)ha[0] + (float)hb[0] + ba.x); l0 = fmaf(gl, wa.x, l0); l1 = fmaf(gl, va.x, l1); \
        gl = gelu_erf((float)ha[1] + (float)hb[1] + ba.y); l0 = fmaf(gl, wa.y, l0); l1 = fmaf(gl, va.y, l1); \
        gl = gelu_erf((float)ha[2] + (float)hb[2] + ba.z); l0 = fmaf(gl, wa.z, l0); l1 = fmaf(gl, va.z, l1); \
        gl = gelu_erf((float)ha[3] + (float)hb[3] + ba.w); l0 = fmaf(gl, wa.w, l0); l1 = fmaf(gl, va.w, l1); \
        gl = gelu_erf((float)ha[4] + (float)hb[4] + bb.x); l0 = fmaf(gl, wb.x, l0); l1 = fmaf(gl, vb.x, l1); \
        gl = gelu_erf((float)ha[5] + (float)hb[5] + bb.y); l0 = fmaf(gl, wb.y, l0); l1 = fmaf(gl, vb.y, l1); \
        gl = gelu_erf((float)ha[6] + (float)hb[6] + bb.z); l0 = fmaf(gl, wb.z, l0); l1 = fmaf(gl, vb.z, l1); \
        gl = gelu_erf((float)ha[7] + (float)hb[7] + bb.w); l0 = fmaf(gl, wb.w, l0); l1 = fmaf(gl, vb.w, l1); \
    }
    GRP(a0, c0v, 0)
    GRP(a1, c1v, 1)
    GRP(a2, c2v, 2)
    GRP(a3, c3v, 3)
#undef GRP
    l0 += __shfl_xor(l0, 1); l0 += __shfl_xor(l0, 2); l0 += __shfl_xor(l0, 4);
    l1 += __shfl_xor(l1, 1); l1 += __shfl_xor(l1, 2); l1 += __shfl_xor(l1, 4);
    if (p == 0) {
        float L0 = l0 + b20, L1 = l1 + b21;
        float mx = fmaxf(L0, L1);
        float ex0 = __expf(L0 - mx), ex1 = __expf(L1 - mx);
        float s = ex0 + ex1, inv = 1.f / s;
        out[1 + 2 * e] = ex0 * inv;
        out[2 + 2 * e] = ex1 * inv;
        float w = lb ? cw1 : cw0;
        wnll_t += w * (mx + logf(s) - (lb ? L1 : L0));
        wsum_t += w;
    }
}

// ---- edge pass: 2-deep register pipeline, 10 edges per 8-lane group (proven round-5) ----
__global__ __launch_bounds__(256, 4)
void edge_mlp6(const f16_t* __restrict__ h, const float* __restrict__ pw,
               const float* __restrict__ b2, const float* __restrict__ cw,
               const int* __restrict__ esrc, const int* __restrict__ edst,
               const int* __restrict__ lab, float* __restrict__ out,
               float* __restrict__ accum)
{
    __shared__ float lds_pw[768];
    __shared__ float red[8];
    const int t = threadIdx.x;
    const int lane = t & 63;
    const int wv = t >> 6;          // 0..3
    const int slot = t >> 3;        // 0..31 (group in block)
    const int p = t & 7;            // 8 lanes per edge

    for (int i = t; i < 768; i += 256) lds_pw[i] = pw[i];

    const float b20 = b2[0], b21 = b2[1];
    const float cw0 = cw[0], cw1 = cw[1];
    const int e0i = blockIdx.x * EBLK + slot;   // 625 * 320 = NE exactly

    float wnll_t = 0.f, wsum_t = 0.f;

    int Xe, Xs, Xd, Xlb, Ye, Ys, Yd, Ylb;
    f16x8 Xa0, Xa1, Xa2, Xa3, Xc0, Xc1, Xc2, Xc3;
    f16x8 Ya0, Ya1, Ya2, Ya3, Yc0, Yc1, Yc2, Yc3;

#define META(B, k) { B##e = e0i + (k) * 32; B##s = esrc[B##e]; B##d = edst[B##e]; B##lb = lab[B##e]; }
#define DATA(B) { \
        const f16_t* sp_ = h + (size_t)B##s * NOUT + p * 8; \
        const f16_t* dp_ = h + (size_t)B##d * NOUT + DD1 + p * 8; \
        B##a0 = *(const f16x8*)(sp_);        B##a1 = *(const f16x8*)(sp_ + 64); \
        B##a2 = *(const f16x8*)(sp_ + 128);  B##a3 = *(const f16x8*)(sp_ + 192); \
        B##c0 = *(const f16x8*)(dp_);        B##c1 = *(const f16x8*)(dp_ + 64); \
        B##c2 = *(const f16x8*)(dp_ + 128);  B##c3 = *(const f16x8*)(dp_ + 192); }

    META(X, 0)
    DATA(X)
    META(Y, 1)
    __syncthreads();   // lds_pw ready

    for (int k = 0; k < EPB; k += 2) {
        DATA(Y)
        {
            const int eC = Xe, lbC = Xlb;
            if (k + 2 < EPB) META(X, k + 2)
            edge_compute(Xa0, Xa1, Xa2, Xa3, Xc0, Xc1, Xc2, Xc3,
                         eC, lbC, p, lds_pw, b20, b21, cw0, cw1, out, wnll_t, wsum_t);
        }
        __builtin_amdgcn_sched_barrier(0);
        if (k + 2 < EPB) DATA(X)
        {
            const int eC = Ye, lbC = Ylb;
            if (k + 3 < EPB) META(Y, k + 3)
            edge_compute(Ya0, Ya1, Ya2, Ya3, Yc0, Yc1, Yc2, Yc3,
                         eC, lbC, p, lds_pw, b20, b21, cw0, cw1, out, wnll_t, wsum_t);
        }
        __builtin_amdgcn_sched_barrier(0);
    }
#undef META
#undef DATA

    wnll_t += __shfl_xor(wnll_t, 8);  wsum_t += __shfl_xor(wsum_t, 8);
    wnll_t += __shfl_xor(wnll_t, 16); wsum_t += __shfl_xor(wsum_t, 16);
    wnll_t += __shfl_xor(wnll_t, 32); wsum_t += __shfl_xor(wsum_t, 32);
    if (lane == 0) { red[wv] = wnll_t; red[4 + wv] = wsum_t; }
    __syncthreads();
    if (t == 0) {
        float a_ = red[0] + red[1] + red[2] + red[3];
        float b_ = red[4] + red[5] + red[6] + red[7];
        atomicAdd(&accum[0], a_);
        atomicAdd(&accum[1], b_);
    }
}

// ================== fallback: fused kernel, pure f32 inputs (no workspace) ==================
__global__ __launch_bounds__(512, 4)
void fused_fallback(const float* __restrict__ xf, const float* __restrict__ w1f,
                    const float* __restrict__ b1, const float* __restrict__ w2,
                    const float* __restrict__ b2, const float* __restrict__ cw,
                    const int* __restrict__ esrc, const int* __restrict__ edst,
                    const int* __restrict__ lab, float* __restrict__ out,
                    float* __restrict__ accum)
{
    __shared__ __align__(16) char smem[65536];
    const int t = threadIdx.x;
    const int lane = t & 63;
    const int wv = t >> 6;
    const int wm = wv & 1;
    const int wn = wv >> 1;
    const int q = lane >> 4;
    const int r = lane & 15;
    const int ebase = blockIdx.x * BM;
    const int r0 = t >> 3;
    const int e1c = (ebase + r0 + 64 < NE) ? (ebase + r0 + 64) : 0;
    const int ns0 = esrc[ebase + r0];
    const int nd0 = edst[ebase + r0];
    const int ns1 = esrc[e1c];
    const int nd1 = edst[e1c];
    const int gsl = (t & 7) ^ (r0 & 7);

    f32x4 acc[4][4];
    #pragma unroll
    for (int a_ = 0; a_ < 4; ++a_)
        #pragma unroll
        for (int b_ = 0; b_ < 4; ++b_) acc[a_][b_] = (f32x4){0.f, 0.f, 0.f, 0.f};

    auto stageA = [&](int kp, char* AbBase) {
        const bool issrc = (kp < 12);
        const int col0 = issrc ? kp * BK : kp * BK - HD;
        #pragma unroll
        for (int i = 0; i < 2; ++i) {
            const int node = i ? (issrc ? ns1 : nd1) : (issrc ? ns0 : nd0);
            bf16_t* lp = (bf16_t*)AbBase + i * 4096 + t * 8;
            const float* gp = xf + (size_t)node * HD + col0 + gsl * 8;
            float4 v0 = ((const float4*)gp)[0];
            float4 v1 = ((const float4*)gp)[1];
            bf16x8 o;
            o[0]=(bf16_t)v0.x; o[1]=(bf16_t)v0.y; o[2]=(bf16_t)v0.z; o[3]=(bf16_t)v0.w;
            o[4]=(bf16_t)v1.x; o[5]=(bf16_t)v1.y; o[6]=(bf16_t)v1.z; o[7]=(bf16_t)v1.w;
            *(bf16x8*)lp = o;
        }
    };

    stageA(0, smem);

    for (int ks = 0; ks < KSTEPS; ++ks) {
        bf16_t* Ac = (bf16_t*)(smem + ((ks & 1) << 14));
        char*   An = smem + ((~ks & 1) << 14);
        bf16_t* Bl = (bf16_t*)(smem + 32768);
        __syncthreads();
        #pragma unroll
        for (int i = 0; i < 4; ++i) {
            const int ci = i * 512 + t;
            bf16_t* lp = Bl + ci * 8;
            const int n = ci & 255, kc = ci >> 8;
            const float* gp = w1f + (size_t)n * TWOH + ks * BK + kc * 8;
            float4 v0 = ((const float4*)gp)[0];
            float4 v1 = ((const float4*)gp)[1];
            bf16x8 o;
            o[0]=(bf16_t)v0.x; o[1]=(bf16_t)v0.y; o[2]=(bf16_t)v0.z; o[3]=(bf16_t)v0.w;
            o[4]=(bf16_t)v1.x; o[5]=(bf16_t)v1.y; o[6]=(bf16_t)v1.z; o[7]=(bf16_t)v1.w;
            *(bf16x8*)lp = o;
        }
        __syncthreads();
        if (ks + 1 < KSTEPS) stageA(ks + 1, An);
        #pragma unroll
        for (int kk = 0; kk < 2; ++kk) {
            bf16x8 af[4];
            const int sl = (kk * 4 + q) ^ (r & 7);
            #pragma unroll
            for (int mb = 0; mb < 4; ++mb) {
                const int m = wm * 64 + mb * 16 + r;
                af[mb] = *(const bf16x8*)(Ac + m * 64 + sl * 8);
            }
            #pragma unroll
            for (int nb = 0; nb < 4; ++nb) {
                bf16x8 bfr = *(const bf16x8*)(Bl + (size_t)(((kk * 4 + q) << 8) + wn * 64 + nb * 16 + r) * 8);
                #pragma unroll
                for (int mb = 0; mb < 4; ++mb)
                    acc[mb][nb] = __builtin_amdgcn_mfma_f32_16x16x32_bf16(af[mb], bfr, acc[mb][nb], 0, 0, 0);
            }
        }
    }

    bf16_t* Hl = (bf16_t*)smem;
    float* red = (float*)(smem + 32768);
    float bias[4];
    #pragma unroll
    for (int nb = 0; nb < 4; ++nb) bias[nb] = b1[wn * 64 + nb * 16 + r];

    float wnll_t = 0.f, wsum_t = 0.f;
    const int ml2 = t >> 3;
    const int p = t & 7;

    #pragma unroll
    for (int half = 0; half < 2; ++half) {
        __syncthreads();
        if (wm == half) {
            #pragma unroll
            for (int mb = 0; mb < 4; ++mb)
                #pragma unroll
                for (int nb = 0; nb < 4; ++nb)
                    #pragma unroll
                    for (int rr = 0; rr < 4; ++rr) {
                        int ml = mb * 16 + q * 4 + rr;
                        int col = wn * 64 + nb * 16 + r;
                        float v = acc[mb][nb][rr] + bias[nb];
                        float g = 0.5f * v * (1.f + erff(v * 0.70710678118654752f));
                        int swcol = ((((col >> 3) ^ (ml & 7)) << 3) | (col & 7));
                        Hl[ml * 256 + swcol] = (bf16_t)g;
                    }
        }
        __syncthreads();
        float l0 = 0.f, l1 = 0.f;
        #pragma unroll
        for (int j = 0; j < 4; ++j) {
            int cj = p * 4 + j;
            bf16x8 hv = *(const bf16x8*)(Hl + ml2 * 256 + ((cj ^ (ml2 & 7)) << 3));
            const float4* w2a = (const float4*)(w2 + cj * 8);
            const float4* w2b = (const float4*)(w2 + 256 + cj * 8);
            float4 wa0 = w2a[0], wa1 = w2a[1], wb0 = w2b[0], wb1 = w2b[1];
            float hf[8];
            #pragma unroll
            for (int u = 0; u < 8; ++u) hf[u] = (float)hv[u];
            l0 += hf[0]*wa0.x + hf[1]*wa0.y + hf[2]*wa0.z + hf[3]*wa0.w
                + hf[4]*wa1.x + hf[5]*wa1.y + hf[6]*wa1.z + hf[7]*wa1.w;
            l1 += hf[0]*wb0.x + hf[1]*wb0.y + hf[2]*wb0.z + hf[3]*wb0.w
                + hf[4]*wb1.x + hf[5]*wb1.y + hf[6]*wb1.z + hf[7]*wb1.w;
        }
        l0 += __shfl_xor(l0, 1); l0 += __shfl_xor(l0, 2); l0 += __shfl_xor(l0, 4);
        l1 += __shfl_xor(l1, 1); l1 += __shfl_xor(l1, 2); l1 += __shfl_xor(l1, 4);
        const int eg = ebase + half * 64 + ml2;
        if (p == 0 && eg < NE) {
            l0 += b2[0]; l1 += b2[1];
            float mx = fmaxf(l0, l1);
            float e0 = expf(l0 - mx), e1 = expf(l1 - mx);
            float s = e0 + e1;
            float inv = 1.f / s;
            out[1 + 2 * eg] = e0 * inv;
            out[2 + 2 * eg] = e1 * inv;
            int lb = lab[eg];
            float w = cw[lb];
            float lpv = ((lb ? l1 : l0) - mx) - logf(s);
            wnll_t -= w * lpv;
            wsum_t += w;
        }
    }
    #pragma unroll
    for (int o = 1; o < 64; o <<= 1) {
        wnll_t += __shfl_xor(wnll_t, o);
        wsum_t += __shfl_xor(wsum_t, o);
    }
    __syncthreads();
    if (lane == 0) { red[wv] = wnll_t; red[8 + wv] = wsum_t; }
    __syncthreads();
    if (t == 0) {
        float a_ = 0.f, b_ = 0.f;
        #pragma unroll
        for (int i = 0; i < 8; ++i) { a_ += red[i]; b_ += red[8 + i]; }
        atomicAdd(&accum[0], a_);
        atomicAdd(&accum[1], b_);
    }
}

extern "C" void kernel_launch(void* const* d_in, const int* in_sizes, int n_in,
                              void* d_out, int out_size, void* d_ws, size_t ws_size,
                              hipStream_t stream)
{
    (void)in_sizes; (void)n_in; (void)out_size;
    const float* x  = (const float*)d_in[0];
    const float* W1 = (const float*)d_in[1];
    const float* b1 = (const float*)d_in[2];
    const float* W2 = (const float*)d_in[3];
    const float* b2 = (const float*)d_in[4];
    const float* cw = (const float*)d_in[5];
    const int* esrc = (const int*)d_in[6];
    const int* edst = (const int*)d_in[7];
    const int* lab  = (const int*)d_in[8];
    float* out = (float*)d_out;
    char* ws = (char*)d_ws;

    float* accum = (float*)ws;
    const size_t off_w1 = 256;
    const size_t w1s_bytes = (size_t)DD1 * TWOH * 2;     // 786432
    const size_t off_pw = off_w1 + w1s_bytes;            // 786688
    const size_t off_h  = off_pw + 3072;                 // 789760
    const size_t h_bytes = (size_t)NN * NOUT * 2;        // 51.2 MB

    (void)hipMemsetAsync(accum, 0, 2 * sizeof(float), stream);

    if (ws_size >= off_h + h_bytes) {
        // tier 1: W1 prep -> node GEMM (reg-staged f32 A, plain barriers) -> edge pass
        bf16_t* w1s = (bf16_t*)(ws + off_w1);
        float* pw = (float*)(ws + off_pw);
        f16_t* h = (f16_t*)(ws + off_h);
        prep_w<<<NB_SWZ + 1, 256, 0, stream>>>(W1, w1s, b1, W2, pw);
        node_gemm5<<<391 * 2, 512, 0, stream>>>(x, w1s, h);
        edge_mlp6<<<NE / EBLK, 256, 0, stream>>>(h, pw, b2, cw, esrc, edst, lab, out, accum);
    } else {
        dim3 grid((NE + BM - 1) / BM);
        fused_fallback<<<grid, 512, 0, stream>>>(
            x, W1, b1, W2, b2, cw, esrc, edst, lab, out, accum);
    }

    finalize_kernel<<<1, 1, 0, stream>>>(out, accum);
}